// Round 10
// baseline (270.801 us; speedup 1.0000x reference)
//
#include <hip/hip_runtime.h>

typedef __attribute__((ext_vector_type(8)))  short short8;
typedef __attribute__((ext_vector_type(4)))  float f32x4;
typedef __attribute__((ext_vector_type(16))) float f32x16;
typedef __attribute__((ext_vector_type(4)))  unsigned short ushort4v;

#define NH   96
#define SEQL 2048
#define DD   128
#define CC   64
#define NCH  32
#define SK   136
#define S64  72
#define SU   72
#define SLOT 4608

__device__ __forceinline__ unsigned short f2bf(float f){
  union { float f; unsigned u; } v; v.f = f;
  unsigned r = v.u + 0x7FFFu + ((v.u >> 16) & 1u);
  return (unsigned short)(r >> 16);
}
__device__ __forceinline__ float bf2f(unsigned short u){
  union { unsigned u; float f; } v; v.u = ((unsigned)u) << 16; return v.f;
}
__device__ __forceinline__ short8 frg(const unsigned short* b, int stride, int row0, int kt, int lane){
  return *(const short8*)&b[(row0 + (lane & 31)) * stride + (kt << 4) + ((lane >> 5) << 3)];
}
__device__ __forceinline__ short8 ifrag(int n0, int kt, int lane){
  const int idx = n0 + (lane & 31) - (kt << 4) - ((lane >> 5) << 3);
  short8 v;
  #pragma unroll
  for (int e = 0; e < 8; ++e) v[e] = (short)((e == idx) ? 0x3F80 : 0);
  return v;
}
#define MM32(A,B,C) __builtin_amdgcn_mfma_f32_32x32x16_bf16(A,B,C,0,0,0)
__device__ __forceinline__ f32x16 z16(){
  return (f32x16){0.f,0.f,0.f,0.f,0.f,0.f,0.f,0.f,0.f,0.f,0.f,0.f,0.f,0.f,0.f,0.f};
}
template<int KTN>
__device__ __forceinline__ f32x16 gemm32(const unsigned short* A, int sa, int m0,
                                         const unsigned short* B, int sb, int n0,
                                         f32x16 acc, int lane){
  #pragma unroll
  for (int kt = 0; kt < KTN; ++kt)
    acc = MM32(frg(A, sa, m0, kt, lane), frg(B, sb, n0, kt, lane), acc);
  return acc;
}
// store C^T row-major (bf16)
__device__ __forceinline__ void stq(unsigned short* buf, int stride, int n0, int m0, int lane, f32x16 v){
  const int nn = n0 + (lane & 31), hh = (lane >> 5) << 2;
  #pragma unroll
  for (int q = 0; q < 4; ++q) {
    ushort4v pv;
    #pragma unroll
    for (int s = 0; s < 4; ++s) pv[s] = f2bf(v[4*q + s]);
    *(ushort4v*)&buf[nn * stride + m0 + 8*q + hh] = pv;
  }
}
__device__ __forceinline__ f32x16 ldq(const unsigned short* buf, int stride, int n0, int m0, int lane){
  f32x16 a;
  const int nn = n0 + (lane & 31), hh = (lane >> 5) << 2;
  #pragma unroll
  for (int q = 0; q < 4; ++q) {
    ushort4v pv = *(const ushort4v*)&buf[nn * stride + m0 + 8*q + hh];
    #pragma unroll
    for (int s = 0; s < 4; ++s) a[4*q + s] = bf2f(pv[s]);
  }
  return a;
}
__device__ __forceinline__ f32x16 pinit(const unsigned short* lo, const unsigned short* hi,
                                        int nt, int m0, int lane){
  const unsigned short* base = (nt ? hi : lo) + (lane & 31) * S64;
  const int hh = (lane >> 5) << 2;
  f32x16 p;
  #pragma unroll
  for (int q = 0; q < 4; ++q) {
    ushort4v t = *(const ushort4v*)&base[m0 + 8*q + hh];
    #pragma unroll
    for (int s = 0; s < 4; ++s) p[4*q + s] = bf2f(t[s]);
  }
  return p;
}
#define BAR() do { asm volatile("s_waitcnt lgkmcnt(0)" ::: "memory"); __builtin_amdgcn_s_barrier(); } while(0)

// ---------------- workspace layout (ushort units per (head,chunk) record) ----------------
#define REC  36864
#define QOFF 0
#define WOFF 8192     // W' row-major [64 tok][128 dk]
#define UOFF 16384    // U^T row-major [128 v][64 tok]
#define KOFF 24576    // KST row-major [128 dk][64 tok]
#define MOFF 32768    // M row-major [64 out-tok][64 src-tok]

// ================================ K1: per-chunk operators (512 thr) ================================
#define AOF 0
#define BOF 9216
#define XS0 17920
#define XS1 22528
#define XS2 27136
#define XS3 31744
#define MRO 36352

__global__ __launch_bounds__(512, 4)
void gdn_prep(const float* __restrict__ Qg, const float* __restrict__ Kg,
              const float* __restrict__ Vg, const float* __restrict__ Gg,
              const float* __restrict__ Bg,
              unsigned short* __restrict__ wsp, float* __restrict__ wcs)
{
  __shared__ unsigned short a[40448];
  __shared__ float s_swv[64], s_swiv[64], s_sbe[64];

  const int tid = threadIdx.x, w = tid >> 6, lane = tid & 63;
  const int mt = (w & 3) >> 1, nt = w & 1;
  const int hc = blockIdx.x, head = hc >> 5, c = hc & 31;
  const int t0 = c * CC;
  const size_t rb = (size_t)head * SEQL * DD + (size_t)t0 * DD;
  const float* kp = Kg + rb;
  const float* qp = Qg + rb;
  const float* vp = Vg + rb;
  const float* gp = Gg + (size_t)head * SEQL + t0;
  const float* bp = Bg + (size_t)head * SEQL + t0;
  unsigned short* rec = wsp + (size_t)hc * REC;

  const int lrow = tid >> 3;
  const int c16  = (tid & 7) * 16;
  const int c8p  = (tid & 7) * 8;

  // ---- ph01: load K/Q, scan g, normalize, stage K~/Q~ (+Q~ -> ws) ----
  f32x4 kr[4], qr[4];
  #pragma unroll
  for (int i = 0; i < 4; ++i) {
    kr[i] = *(const f32x4*)(kp + (size_t)lrow * DD + c16 + 4*i);
    qr[i] = *(const f32x4*)(qp + (size_t)lrow * DD + c16 + 4*i);
  }
  float gl = gp[lane], bl = bp[lane];
  float sc = gl;
  #pragma unroll
  for (int d = 1; d < 64; d <<= 1) { float t = __shfl_up(sc, d); if (lane >= d) sc += t; }
  float wv = __expf(sc);
  if (w == 0) { s_swv[lane] = wv; s_swiv[lane] = __expf(-sc); s_sbe[lane] = bl; }
  float ssk = 0.f, ssq = 0.f;
  #pragma unroll
  for (int i = 0; i < 4; ++i) {
    ssk += kr[i][0]*kr[i][0] + kr[i][1]*kr[i][1] + kr[i][2]*kr[i][2] + kr[i][3]*kr[i][3];
    ssq += qr[i][0]*qr[i][0] + qr[i][1]*qr[i][1] + qr[i][2]*qr[i][2] + qr[i][3]*qr[i][3];
  }
  ssk += __shfl_xor(ssk, 1); ssk += __shfl_xor(ssk, 2); ssk += __shfl_xor(ssk, 4);
  ssq += __shfl_xor(ssq, 1); ssq += __shfl_xor(ssq, 2); ssq += __shfl_xor(ssq, 4);
  const float ik = 1.f / fmaxf(sqrtf(ssk), 1e-6f);
  const float wl = __shfl(wv, lrow);
  const float iq = 0.08838834764831845f / fmaxf(sqrtf(ssq), 1e-6f) * wl;
  #pragma unroll
  for (int i = 0; i < 4; ++i) {
    ushort4v pk, pq;
    #pragma unroll
    for (int r = 0; r < 4; ++r) { pk[r] = f2bf(kr[i][r]*ik); pq[r] = f2bf(qr[i][r]*iq); }
    *(ushort4v*)&a[AOF + lrow*SK + c16 + 4*i] = pk;
    *(ushort4v*)&a[BOF + lrow*SK + c16 + 4*i] = pq;
    *(ushort4v*)(rec + QOFF + lrow*DD + c16 + 4*i) = pq;
  }
  BAR();

  // ---- ph2 (8 jobs): w<4: KK^T -> X0,X0T ; w>=4: KQ~ -> M direct to ws ----
  if (w < 4) {
    f32x16 ckk = gemm32<8>(a+AOF, SK, 32*mt, a+AOF, SK, 32*nt, z16(), lane);
    const int nn = 32*nt + (lane & 31), hh = (lane >> 5) << 2;
    const float ben = s_sbe[nn], wvn = s_swv[nn], sin = s_swiv[nn];
    #pragma unroll
    for (int q = 0; q < 4; ++q) {
      ushort4v xT, xR;
      #pragma unroll
      for (int si = 0; si < 4; ++si) {
        const int r = 4*q + si, mm = 32*mt + 8*q + hh + si;
        const float svm = s_swv[mm], sim = s_swiv[mm], bem = s_sbe[mm];
        xT[si] = (mm > nn) ? f2bf(bem*svm*sin*ckk[r]) : 0;
        xR[si] = (nn > mm) ? f2bf(ben*wvn*sim*ckk[r]) : 0;
      }
      const int off = nn*S64 + 32*mt + 8*q + hh;
      *(ushort4v*)&a[XS1 + off] = xT;
      *(ushort4v*)&a[XS0 + off] = xR;
    }
  } else {
    f32x16 ckq = gemm32<8>(a+AOF, SK, 32*mt, a+BOF, SK, 32*nt, z16(), lane);
    const int nn = 32*nt + (lane & 31), hh = (lane >> 5) << 2;
    #pragma unroll
    for (int q = 0; q < 4; ++q) {
      ushort4v mv;
      #pragma unroll
      for (int si = 0; si < 4; ++si) {
        const int r = 4*q + si, mm = 32*mt + 8*q + hh + si;
        mv[si] = (mm <= nn) ? f2bf(ckq[r]*s_swiv[mm]) : 0;
      }
      *(ushort4v*)(rec + MOFF + nn*64 + 32*mt + 8*q + hh) = mv;
    }
  }
  BAR();

  // ---- ph3: X1 = X0^2 dual ; P0 = I - X0 ; issue V loads ----
  f32x4 vr[4];
  #pragma unroll
  for (int i = 0; i < 4; ++i)
    vr[i] = *(const f32x4*)(vp + (size_t)lrow * DD + c16 + 4*i);
  if (w < 4) {
    f32x16 c1 = gemm32<4>(a+XS0, S64, 32*mt, a+XS1, S64, 32*nt, z16(), lane);
    stq(a+XS3, S64, 32*nt, 32*mt, lane, c1);
  } else {
    f32x16 c2 = gemm32<4>(a+XS1, S64, 32*mt, a+XS0, S64, 32*nt, z16(), lane);
    stq(a+XS2, S64, 32*nt, 32*mt, lane, c2);
  }
  {
    unsigned short* p0 = a + ((lrow < 32) ? BOF : BOF+2304) + (lrow & 31)*S64;
    const unsigned short* x0 = a + XS0 + lrow*S64;
    short8 xv = *(const short8*)&x0[c8p];
    short8 ov;
    #pragma unroll
    for (int e = 0; e < 8; ++e) {
      const int col = c8p + e;
      ov[e] = (short)f2bf(((col == lrow) ? 1.f : 0.f) - bf2f((unsigned short)xv[e]));
    }
    *(short8*)&p0[c8p] = ov;
  }
  BAR();

  // ---- ph4 (lev0): X2 dual + P1 ----
  if (w < 4) {
    f32x16 c1 = gemm32<4>(a+XS2, S64, 32*mt, a+XS3, S64, 32*nt, z16(), lane);
    stq(a+XS1, S64, 32*nt, 32*mt, lane, c1);
    f32x16 p = pinit(a+BOF, a+BOF+2304, nt, 32*mt, lane);
    p = gemm32<4>(a+XS3, S64, 32*mt, (nt ? a+BOF+2304 : a+BOF), S64, 0, p, lane);
    stq((nt ? a+MRO : a+BOF+SLOT), S64, 0, 32*mt, lane, p);
  } else {
    f32x16 c2 = gemm32<4>(a+XS3, S64, 32*mt, a+XS2, S64, 32*nt, z16(), lane);
    stq(a+XS0, S64, 32*nt, 32*mt, lane, c2);
  }
  BAR();

  // ---- ph5 (lev1): A^8 + P2 ----
  if (w < 4) {
    f32x16 c1 = gemm32<4>(a+XS0, S64, 32*mt, a+XS1, S64, 32*nt, z16(), lane);
    stq(a+XS2, S64, 32*nt, 32*mt, lane, c1);   // A^8 rm
  } else {
    f32x16 p = pinit(a+BOF+SLOT, a+MRO, nt, 32*mt, lane);
    p = gemm32<4>(a+XS1, S64, 32*mt, (nt ? a+MRO : a+BOF+SLOT), S64, 0, p, lane);
    stq((nt ? a+BOF+2304 : a+BOF), S64, 0, 32*mt, lane, p);
  }
  BAR();

  // ---- ph6: T = P2 + A^8*P2 ; VT scatter ----
  if (w < 4) {
    f32x16 p = pinit(a+BOF, a+BOF+2304, nt, 32*mt, lane);
    p = gemm32<4>(a+XS2, S64, 32*mt, (nt ? a+BOF+2304 : a+BOF), S64, 0, p, lane);
    stq((nt ? a+MRO : a+BOF+SLOT), S64, 0, 32*mt, lane, p);
  }
  #pragma unroll
  for (int i = 0; i < 4; ++i)
    #pragma unroll
    for (int r = 0; r < 4; ++r)
      a[XS0 + (c16 + 4*i + r)*S64 + lrow] = f2bf(vr[i][r]);
  BAR();

  // ---- ph7: T2/T3 elementwise ; KT identity -> XS2..XS3 ; KST -> ws ----
  {
    unsigned short* trow  = a + ((lrow < 32) ? BOF+SLOT : MRO) + (lrow & 31)*S64;
    unsigned short* t3row = a + ((lrow < 32) ? BOF : BOF+2304) + (lrow & 31)*S64;
    short8 tv = *(const short8*)&trow[c8p];
    short8 o2, o3;
    #pragma unroll
    for (int e = 0; e < 8; ++e) {
      const int j = c8p + e;
      const float t = bf2f((unsigned short)tv[e]);
      o2[e] = (short)f2bf(-t * s_sbe[j] * s_swv[j]);
      o3[e] = (short)f2bf( t * s_sbe[j]);
    }
    *(short8*)&trow[c8p]  = o2;   // T2
    *(short8*)&t3row[c8p] = o3;   // T3
  }
  {
    const int j = w >> 2, d4 = w & 3;
    const float wcv = s_swv[63];
    f32x16 ckt = z16();
    #pragma unroll
    for (int kk = 0; kk < 2; ++kk) {
      const int kt = 2*d4 + kk;
      ckt = MM32(frg(a+AOF, SK, 32*j, kt, lane), ifrag(32*d4, kt, lane), ckt);
    }
    stq(a+XS2, S64, 32*d4, 32*j, lane, ckt);
    const int nn = 32*d4 + (lane & 31), hh = (lane >> 5) << 2;
    #pragma unroll
    for (int q = 0; q < 4; ++q) {
      ushort4v o;
      #pragma unroll
      for (int si = 0; si < 4; ++si) {
        const int tok = 32*j + 8*q + hh + si;
        o[si] = f2bf(ckt[4*q+si] * wcv * s_swiv[tok]);
      }
      *(ushort4v*)(rec + KOFF + nn*64 + 32*j + 8*q + hh) = o;
    }
  }
  BAR();

  // ---- ph8: W' -> ws ; U^T -> ws ; wc ----
  {
    const int j = w >> 2, d4 = w & 3;
    const int nn = lane & 31, hh = (lane >> 5) << 2;
    f32x16 cw = gemm32<4>(a+XS2, S64, 32*d4, (j ? a+MRO : a+BOF+SLOT), S64, 0, z16(), lane);
    #pragma unroll
    for (int q = 0; q < 4; ++q) {
      ushort4v pw;
      #pragma unroll
      for (int si = 0; si < 4; ++si) pw[si] = f2bf(cw[4*q+si]);
      *(ushort4v*)(rec + WOFF + (32*j + nn)*128 + 32*d4 + 8*q + hh) = pw;
    }
    f32x16 cu = gemm32<4>((j ? a+BOF+2304 : a+BOF), S64, 0, a+XS0, S64, 32*d4, z16(), lane);
    #pragma unroll
    for (int q = 0; q < 4; ++q) {
      ushort4v pu;
      #pragma unroll
      for (int si = 0; si < 4; ++si) pu[si] = f2bf(cu[4*q+si]);
      *(ushort4v*)(rec + UOFF + (32*d4 + nn)*64 + 32*j + 8*q + hh) = pu;
    }
    if (tid == 0) wcs[hc] = s_swv[63];
  }
}

// ================================ K2: sequential state scan (register-direct, macro-expanded) ================================
// Operand buffers are NAMED arrays indexed only by unrolled constant indices;
// their address never escapes (no lambda/function pointer args) -> SROA keeps them in VGPRs.
#define ISSUE(P, cval) do {                                                              \
    const unsigned short* rec_ = recs + (size_t)(cval) * REC;                            \
    if (dw) {                                                                            \
      _Pragma("unroll")                                                                  \
      for (int kt = 0; kt < 8; ++kt)                                                     \
        A##P##_[kt] = *(const short8*)(rec_ + WOFF + (32*th + l31)*128 + kt*16 + hi8);   \
      const int vrow_ = vh*64 + 32*vc + l31;                                             \
      _Pragma("unroll")                                                                  \
      for (int q = 0; q < 4; ++q)                                                        \
        U##P##_[q] = *(const ushort4v*)(rec_ + UOFF + vrow_*64 + 32*th + 8*q + hh);      \
    } else {                                                                             \
      _Pragma("unroll")                                                                  \
      for (int kt = 0; kt < 8; ++kt)                                                     \
        A##P##_[kt] = *(const short8*)(rec_ + QOFF + (32*th + l31)*128 + kt*16 + hi8);   \
      _Pragma("unroll")                                                                  \
      for (int kt = 0; kt < 4; ++kt)                                                     \
        C##P##_[kt] = *(const short8*)(rec_ + MOFF + (32*th + l31)*64 + kt*16 + hi8);    \
    }                                                                                    \
    _Pragma("unroll")                                                                    \
    for (int kt = 0; kt < 4; ++kt)                                                       \
      B##P##_[kt] = *(const short8*)(rec_ + KOFF + (32*mtS + l31)*64 + kt*16 + hi8);     \
    wc##P = wcsh[cval];                                                                  \
  } while(0)

#define BODY(P, PN, cval) do {                                                           \
    if ((cval) + 1 < NCH) ISSUE(PN, (cval) + 1);                                         \
    f32x16 oq_ = z16();                                                                  \
    if (dw) {                                                                            \
      f32x16 d_ = z16();                                                                 \
      _Pragma("unroll")                                                                  \
      for (int kt = 0; kt < 8; ++kt)                                                     \
        d_ = MM32(A##P##_[kt], frg(sS, SK, 32*vc, kt, lane), d_);                        \
      const int nn_ = 32*vc + l31;                                                       \
      _Pragma("unroll")                                                                  \
      for (int q = 0; q < 4; ++q) {                                                      \
        ushort4v pt_;                                                                    \
        _Pragma("unroll")                                                                \
        for (int si = 0; si < 4; ++si)                                                   \
          pt_[si] = f2bf(d_[4*q + si] + bf2f(U##P##_[q][si]));                           \
        *(ushort4v*)&sD[nn_*SU + 32*th + 8*q + hh] = pt_;                                \
      }                                                                                  \
    } else {                                                                             \
      _Pragma("unroll")                                                                  \
      for (int kt = 0; kt < 8; ++kt)                                                     \
        oq_ = MM32(A##P##_[kt], frg(sS, SK, 32*vc, kt, lane), oq_);                      \
    }                                                                                    \
    BAR();                                                                               \
    {                                                                                    \
      f32x16 sa_;                                                                        \
      _Pragma("unroll")                                                                  \
      for (int r = 0; r < 16; ++r) sa_[r] = s[r] * wc##P;                                \
      _Pragma("unroll")                                                                  \
      for (int kt = 0; kt < 4; ++kt)                                                     \
        sa_ = MM32(B##P##_[kt], frg(sD, SU, 32*ntS, kt, lane), sa_);                     \
      s = sa_;                                                                           \
    }                                                                                    \
    if (!dw) {                                                                           \
      f32x16 o_ = oq_;                                                                   \
      _Pragma("unroll")                                                                  \
      for (int kt = 0; kt < 4; ++kt)                                                     \
        o_ = MM32(C##P##_[kt], frg(sD, SU, 32*vc, kt, lane), o_);                        \
      float* ob_ = op + (size_t)((cval)*CC + 32*th) * DD + 32*vc + l31;                  \
      _Pragma("unroll")                                                                  \
      for (int q = 0; q < 4; ++q)                                                        \
        _Pragma("unroll")                                                                \
        for (int si = 0; si < 4; ++si)                                                   \
          ob_[(size_t)(si + 8*q + hh) * DD] = o_[4*q + si];                              \
    }                                                                                    \
    stq(sS, SK, 32*ntS, 32*mtS, lane, s);                                                \
    BAR();                                                                               \
  } while(0)

__global__ __launch_bounds__(512, 1)
void gdn_scan(const unsigned short* __restrict__ wsp, const float* __restrict__ wcs,
              float* __restrict__ Out, float* __restrict__ FS)
{
  __shared__ unsigned short sS[64*SK];   // S^T [v 64][dk 128]
  __shared__ unsigned short sD[64*SU];   // Delta^T [v 64][tok 64]

  const int tid = threadIdx.x, w = tid >> 6, lane = tid & 63;
  const int head = blockIdx.x % NH, vh = blockIdx.x / NH;   // vh-pair on same XCD
  const unsigned short* recs = wsp + (size_t)head * NCH * REC;
  const float* wcsh = wcs + head * NCH;
  float* op = Out + (size_t)head * SEQL * DD + vh * 64;

  const int mtS = w >> 1, ntS = w & 1;       // S-tile (dk, v-col)
  const bool dw = (w < 4);                   // delta waves vs Oq/out waves
  const int th  = (w & 3) >> 1;              // tok-half (both roles)
  const int vc  = w & 1;                     // v-col (both roles)
  const int l31 = lane & 31, hi8 = (lane >> 5) << 3, hh = (lane >> 5) << 2;

  f32x16 s = z16();

  short8 A0_[8], B0_[4], C0_[4]; ushort4v U0_[4]; float wc0 = 0.f;
  short8 A1_[8], B1_[4], C1_[4]; ushort4v U1_[4]; float wc1 = 0.f;

  ISSUE(0, 0);
  stq(sS, SK, 32*ntS, 32*mtS, lane, s);   // S0 = 0
  BAR();

  for (int cc = 0; cc < NCH; cc += 2) {
    BODY(0, 1, cc);
    BODY(1, 0, cc + 1);
  }

  // final state
  {
    float* fsp = FS + (size_t)head * DD * DD + vh * 64;
    const int nn = 32*ntS + l31;
    #pragma unroll
    for (int q = 0; q < 4; ++q)
      #pragma unroll
      for (int si = 0; si < 4; ++si)
        fsp[(size_t)(32*mtS + si + 8*q + hh) * DD + nn] = s[4*q + si];
  }
}

// ================================ fallback (R3, verified) ================================
__global__ __launch_bounds__(512, 1)
void gdn_chunk2(const float* __restrict__ Qg, const float* __restrict__ Kg,
                const float* __restrict__ Vg, const float* __restrict__ Gg,
                const float* __restrict__ Bg,
                float* __restrict__ Out, float* __restrict__ FS)
{
  __shared__ __align__(16) unsigned short sKc[64*SK];
  __shared__ __align__(16) unsigned short sQc[64*SK];
  __shared__ __align__(16) unsigned short sS0T[64*SK];
  __shared__ __align__(16) unsigned short sVc[64*S64];
  __shared__ __align__(16) unsigned short sVT[64*S64];
  __shared__ __align__(16) unsigned short sM[64*S64];
  __shared__ __align__(16) unsigned short sAr[8*SLOT];
  __shared__ float sbe2[2][64], swv2[2][64], swiv2[2][64];

  const int tid  = threadIdx.x;
  const int w    = tid >> 6;
  const int lane = tid & 63;
  const int half = w >> 2;
  const int j    = w & 3;
  const int mt   = j >> 1, nt = j & 1;
  const int mtS  = w >> 1, ntS = w & 1;
  const int mtK  = w >> 2, ntK = w & 3;
  const int head = blockIdx.x % NH;
  const int vh   = blockIdx.x / NH;

  const size_t rb = (size_t)head * SEQL * DD;
  const float* qp = Qg + rb;
  const float* kp = Kg + rb;
  const float* vp = Vg + rb + vh * 64;
  const float* gp = Gg + (size_t)head * SEQL;
  const float* bp = Bg + (size_t)head * SEQL;
  float* op  = Out + rb + vh * 64;
  float* fsp = FS + (size_t)head * DD * DD + vh * 64;

  const int lrow = tid >> 3;
  const int c16  = (tid & 7) * 16;
  const int c8   = (tid & 7) * 8;

  unsigned short* const sl0 = sAr + 0*SLOT;
  unsigned short* const sl1 = sAr + 1*SLOT;
  unsigned short* const sl2 = sAr + 2*SLOT;
  unsigned short* const sl3 = sAr + 3*SLOT;
  unsigned short* const sl4 = sAr + 4*SLOT;
  unsigned short* const sl5 = sAr + 5*SLOT;
  unsigned short* const sl6 = sAr + 6*SLOT;
  unsigned short* const sl7 = sAr + 7*SLOT;

  f32x16 s = z16(), oacc = z16();
  f32x4 kr[4], qr[4], vr[2]; float gr = 0.f, br = 0.f;

  auto prefetch = [&](int t0p){
    const float* kb = kp + (size_t)(t0p + lrow) * DD + c16;
    const float* qb = qp + (size_t)(t0p + lrow) * DD + c16;
    const float* vb = vp + (size_t)(t0p + lrow) * DD + c8;
    #pragma unroll
    for (int i = 0; i < 4; ++i) { kr[i] = *(const f32x4*)(kb + 4*i); qr[i] = *(const f32x4*)(qb + 4*i); }
    #pragma unroll
    for (int i = 0; i < 2; ++i) vr[i] = *(const f32x4*)(vb + 4*i);
    if (w == 7) { gr = gp[t0p + lane]; br = bp[t0p + lane]; }
  };
  auto scan_to = [&](int p){
    if (w == 7) {
      float sc = gr;
      #pragma unroll
      for (int d = 1; d < 64; d <<= 1) { float t = __shfl_up(sc, d); if (lane >= d) sc += t; }
      swv2[p][lane]  = __expf(sc);
      swiv2[p][lane] = __expf(-sc);
      sbe2[p][lane]  = br;
    }
  };

  prefetch(0);
  scan_to(0);
  BAR();

  for (int tc = 0; tc < NCH; ++tc) {
    const int t0 = tc * CC;
    const int cur = tc & 1, nxt = cur ^ 1;
    {
      float ssk = 0.f, ssq = 0.f;
      #pragma unroll
      for (int i = 0; i < 4; ++i) {
        ssk += kr[i][0]*kr[i][0] + kr[i][1]*kr[i][1] + kr[i][2]*kr[i][2] + kr[i][3]*kr[i][3];
        ssq += qr[i][0]*qr[i][0] + qr[i][1]*qr[i][1] + qr[i][2]*qr[i][2] + qr[i][3]*qr[i][3];
      }
      ssk += __shfl_xor(ssk, 1); ssk += __shfl_xor(ssk, 2); ssk += __shfl_xor(ssk, 4);
      ssq += __shfl_xor(ssq, 1); ssq += __shfl_xor(ssq, 2); ssq += __shfl_xor(ssq, 4);
      const float ik = 1.f / fmaxf(sqrtf(ssk), 1e-6f);
      const float iq = 0.08838834764831845f / fmaxf(sqrtf(ssq), 1e-6f) * swv2[cur][lrow];
      #pragma unroll
      for (int i = 0; i < 4; ++i) {
        ushort4v pk, pq;
        #pragma unroll
        for (int r = 0; r < 4; ++r) { pk[r] = f2bf(kr[i][r] * ik); pq[r] = f2bf(qr[i][r] * iq); }
        *(ushort4v*)&sKc[lrow*SK + c16 + 4*i] = pk;
        *(ushort4v*)&sQc[lrow*SK + c16 + 4*i] = pq;
      }
      #pragma unroll
      for (int i = 0; i < 2; ++i) {
        ushort4v pv;
        #pragma unroll
        for (int r = 0; r < 4; ++r) pv[r] = f2bf(vr[i][r]);
        *(ushort4v*)&sVc[lrow*S64 + c8 + 4*i] = pv;
      }
    }
    stq(sS0T, SK, 32*ntS, 32*mtS, lane, s);
    prefetch(tc < NCH-1 ? (tc+1)*CC : t0);
    BAR();

    if (half == 0) {
      f32x16 aa = gemm32<8>(sKc, SK, 32*mt, sKc, SK, 32*nt, z16(), lane);
      const int nn = 32*nt + (lane & 31), hh = (lane >> 5) << 2;
      #pragma unroll
      for (int q = 0; q < 4; ++q) {
        ushort4v pR, pL, pPT, pP;
        #pragma unroll
        for (int si = 0; si < 4; ++si) {
          const int r = 4*q + si, mm = 32*mt + 8*q + hh + si;
          const float S = aa[r];
          const float av  = (mm > nn) ? sbe2[cur][mm]*swv2[cur][mm]*swiv2[cur][nn]*S : 0.f;
          const float atr = (nn > mm) ? sbe2[cur][nn]*swv2[cur][nn]*swiv2[cur][mm]*S : 0.f;
          pR[si]  = f2bf(av);
          pL[si]  = f2bf(atr);
          pPT[si] = f2bf(((mm==nn)?1.f:0.f) - av);
          pP[si]  = f2bf(((mm==nn)?1.f:0.f) - atr);
        }
        const int off = nn*S64 + 32*mt + 8*q + hh;
        *(ushort4v*)&sl1[off] = pR;
        *(ushort4v*)&sl0[off] = pL;
        *(ushort4v*)&sl5[off] = pPT;
        *(ushort4v*)&sl4[off] = pP;
      }
    } else {
      f32x16 aa = gemm32<8>(sKc, SK, 32*mt, sQc, SK, 32*nt, z16(), lane);
      const int nn = 32*nt + (lane & 31), hh = (lane >> 5) << 2;
      #pragma unroll
      for (int q = 0; q < 4; ++q) {
        ushort4v pv;
        #pragma unroll
        for (int si = 0; si < 4; ++si) {
          const int r = 4*q + si, mm = 32*mt + 8*q + hh + si;
          pv[si] = f2bf((mm <= nn) ? aa[r]*swiv2[cur][mm] : 0.f);
        }
        *(ushort4v*)&sM[nn*S64 + 32*mt + 8*q + hh] = pv;
      }
    }
    BAR();

    if (half == 0) {
      f32x16 aa = gemm32<4>(sl0, S64, 32*mt, sl1, S64, 32*nt, z16(), lane);
      stq(sl3, S64, 32*nt, 32*mt, lane, aa);
      f32x16 bb = z16();
      #pragma unroll
      for (int kk = 0; kk < 2; ++kk) {
        const int kt = 2*nt + kk;
        bb = MM32(frg(sVc, S64, 32*mt, kt, lane), ifrag(32*nt, kt, lane), bb);
      }
      stq(sVT, S64, 32*nt, 32*mt, lane, bb);
    } else {
      f32x16 aa = gemm32<4>(sl1, S64, 32*mt, sl0, S64, 32*nt, z16(), lane);
      stq(sl2, S64, 32*nt, 32*mt, lane, aa);
      oacc = gemm32<8>(sQc, SK, 32*mt, sS0T, SK, 32*nt, z16(), lane);
    }
    BAR();

    {
      unsigned short* const inL[3]   = { sl2, sl0, sl2 };
      unsigned short* const inR[3]   = { sl3, sl1, sl3 };
      unsigned short* const outL[3]  = { sl0, sl2, sl0 };
      unsigned short* const outR[3]  = { sl1, sl3, sl1 };
      unsigned short* const inP[3]   = { sl4, sl7, sl5 };
      unsigned short* const inPT[3]  = { sl5, sl6, sl4 };
      unsigned short* const outP[3]  = { sl7, sl5, sl7 };
      unsigned short* const outPT[3] = { sl6, sl4, sl6 };
      #pragma unroll
      for (int lev = 0; lev < 3; ++lev) {
        if (half == 0) {
          f32x16 aa = gemm32<4>(inL[lev], S64, 32*mt, inR[lev], S64, 32*nt, z16(), lane);
          stq(outR[lev], S64, 32*nt, 32*mt, lane, aa);
          f32x16 p = ldq(inPT[lev], S64, 32*nt, 32*mt, lane);
          p = gemm32<4>(inP[lev], S64, 32*mt, inR[lev], S64, 32*nt, p, lane);
          stq(outPT[lev], S64, 32*nt, 32*mt, lane, p);
        } else {
          f32x16 aa = gemm32<4>(inR[lev], S64, 32*mt, inL[lev], S64, 32*nt, z16(), lane);
          stq(outL[lev], S64, 32*nt, 32*mt, lane, aa);
          f32x16 p = ldq(inP[lev], S64, 32*nt, 32*mt, lane);
          p = gemm32<4>(inR[lev], S64, 32*mt, inP[lev], S64, 32*nt, p, lane);
          stq(outP[lev], S64, 32*nt, 32*mt, lane, p);
        }
        BAR();
      }
    }

    if (half == 0) {
      f32x16 aa = gemm32<4>(sl0, S64, 32*mt, sl1, S64, 32*nt, z16(), lane);
      stq(sl2, S64, 32*nt, 32*mt, lane, aa);
    } else {
      f32x16 p = ldq(sl7, S64, 32*nt, 32*mt, lane);
      p = gemm32<4>(sl1, S64, 32*mt, sl7, S64, 32*nt, p, lane);
      stq(sl4, S64, 32*nt, 32*mt, lane, p);
    }
    BAR();

    if (half == 0) {
      f32x16 p = ldq(sl4, S64, 32*nt, 32*mt, lane);
      p = gemm32<4>(sl2, S64, 32*mt, sl4, S64, 32*nt, p, lane);
      const int nn = 32*nt + (lane & 31), hh = (lane >> 5) << 2;
      #pragma unroll
      for (int q = 0; q < 4; ++q) {
        ushort4v p2, p3;
        #pragma unroll
        for (int si = 0; si < 4; ++si) {
          const int r = 4*q + si, mm = 32*mt + 8*q + hh + si;
          const float t = p[r];
          p2[si] = f2bf(-t * sbe2[cur][mm] * swv2[cur][mm]);
          p3[si] = f2bf( t * sbe2[cur][mm]);
        }
        const int off = nn*S64 + 32*mt + 8*q + hh;
        *(ushort4v*)&sl1[off] = p2;
        *(ushort4v*)&sl5[off] = p3;
      }
    } else {
      f32x16 zz = gemm32<8>(sKc, SK, 32*mt, sS0T, SK, 32*nt, z16(), lane);
      stq(sl0, S64, 32*nt, 32*mt, lane, zz);
    }
    {
      f32x16 aa = z16();
      #pragma unroll
      for (int kk = 0; kk < 2; ++kk) {
        const int kt = 2*ntK + kk;
        aa = MM32(frg(sKc, SK, 32*mtK, kt, lane), ifrag(32*ntK, kt, lane), aa);
      }
      stq(sl6, S64, 32*ntK, 32*mtK, lane, aa);
    }
    BAR();

    if (half == 0) {
      f32x16 d = gemm32<4>(sl5, S64, 32*mt, sVT, S64, 32*nt, z16(), lane);
      d = gemm32<4>(sl1, S64, 32*mt, sl0, S64, 32*nt, d, lane);
      const int nn = 32*nt + (lane & 31), hh = (lane >> 5) << 2;
      const float w63 = swv2[cur][63];
      #pragma unroll
      for (int q = 0; q < 4; ++q) {
        ushort4v pt, ps;
        #pragma unroll
        for (int si = 0; si < 4; ++si) {
          const int r = 4*q + si, mm = 32*mt + 8*q + hh + si;
          pt[si] = f2bf(d[r]);
          ps[si] = f2bf(d[r] * w63 * swiv2[cur][mm]);
        }
        const int off = nn*S64 + 32*mt + 8*q + hh;
        *(ushort4v*)&sl3[off] = pt;
        *(ushort4v*)&sl2[off] = ps;
      }
    }
    scan_to(nxt);
    {
      const float w63 = swv2[cur][63];
      #pragma unroll
      for (int r = 0; r < 16; ++r) s[r] *= w63;
    }
    BAR();

    s = gemm32<4>(sl6, S64, 32*mtS, sl2, S64, 32*ntS, s, lane);
    if (half == 1) {
      f32x16 o = oacc;
      o = gemm32<4>(sM, S64, 32*mt, sl3, S64, 32*nt, o, lane);
      const int nn = 32*nt + (lane & 31), hh = (lane >> 5) << 2;
      #pragma unroll
      for (int q = 0; q < 4; ++q)
        #pragma unroll
        for (int si = 0; si < 4; ++si)
          op[(size_t)(t0 + 32*mt + 8*q + hh + si) * DD + nn] = o[4*q + si];
    }
    BAR();
  }

  {
    const int nn = 32*ntS + (lane & 31), hh = (lane >> 5) << 2;
    #pragma unroll
    for (int q = 0; q < 4; ++q)
      #pragma unroll
      for (int si = 0; si < 4; ++si)
        fsp[(size_t)(32*mtS + 8*q + hh + si) * DD + nn] = s[4*q + si];
  }
}

extern "C" void kernel_launch(void* const* d_in, const int* in_sizes, int n_in,
                              void* d_out, int out_size, void* d_ws, size_t ws_size,
                              hipStream_t stream) {
  const float* Q = (const float*)d_in[0];
  const float* K = (const float*)d_in[1];
  const float* V = (const float*)d_in[2];
  const float* G = (const float*)d_in[3];
  const float* B = (const float*)d_in[4];
  float* Out = (float*)d_out;
  float* FS  = Out + (size_t)NH * SEQL * DD;

  const size_t WS_NEED = (size_t)NH * NCH * REC * 2 + (size_t)NH * NCH * 4;
  if (ws_size >= WS_NEED) {
    unsigned short* wsp = (unsigned short*)d_ws;
    float* wcs = (float*)(wsp + (size_t)NH * NCH * REC);
    hipLaunchKernelGGL(gdn_prep, dim3(NH*NCH), dim3(512), 0, stream, Q, K, V, G, B, wsp, wcs);
    hipLaunchKernelGGL(gdn_scan, dim3(NH*2), dim3(512), 0, stream, wsp, wcs, Out, FS);
  } else {
    hipLaunchKernelGGL(gdn_chunk2, dim3(NH*2), dim3(512), 0, stream, Q, K, V, G, B, Out, FS);
  }
}

// Round 12
// 230.767 us; speedup vs baseline: 1.1735x; 1.1735x over previous
//
#include <hip/hip_runtime.h>
#include <hip/hip_bf16.h>

typedef __attribute__((ext_vector_type(8)))  short short8;
typedef __attribute__((ext_vector_type(4)))  float f32x4;
typedef __attribute__((ext_vector_type(16))) float f32x16;
typedef __attribute__((ext_vector_type(4)))  unsigned short ushort4v;

#define NH   96
#define SEQL 2048
#define DD   128
#define CC   64
#define NCH  32
#define SK   136
#define S64  72
#define SU   72
#define SLOT 4608

// Native RNE f32->bf16 via HIP intrinsic (lowers to HW cvt op; backend can pack pairs).
__device__ __forceinline__ unsigned short f2bf(float f){
  __hip_bfloat16 h = __float2bfloat16(f);
  union { __hip_bfloat16 h; unsigned short u; } v; v.h = h; return v.u;
}
__device__ __forceinline__ float bf2f(unsigned short u){
  union { unsigned u; float f; } v; v.u = ((unsigned)u) << 16; return v.f;
}
__device__ __forceinline__ short8 frg(const unsigned short* b, int stride, int row0, int kt, int lane){
  return *(const short8*)&b[(row0 + (lane & 31)) * stride + (kt << 4) + ((lane >> 5) << 3)];
}
__device__ __forceinline__ short8 ifrag(int n0, int kt, int lane){
  const int idx = n0 + (lane & 31) - (kt << 4) - ((lane >> 5) << 3);
  short8 v;
  #pragma unroll
  for (int e = 0; e < 8; ++e) v[e] = (short)((e == idx) ? 0x3F80 : 0);
  return v;
}
#define MM32(A,B,C) __builtin_amdgcn_mfma_f32_32x32x16_bf16(A,B,C,0,0,0)
__device__ __forceinline__ f32x16 z16(){
  return (f32x16){0.f,0.f,0.f,0.f,0.f,0.f,0.f,0.f,0.f,0.f,0.f,0.f,0.f,0.f,0.f,0.f};
}
template<int KTN>
__device__ __forceinline__ f32x16 gemm32(const unsigned short* A, int sa, int m0,
                                         const unsigned short* B, int sb, int n0,
                                         f32x16 acc, int lane){
  #pragma unroll
  for (int kt = 0; kt < KTN; ++kt)
    acc = MM32(frg(A, sa, m0, kt, lane), frg(B, sb, n0, kt, lane), acc);
  return acc;
}
// store C^T row-major (bf16)
__device__ __forceinline__ void stq(unsigned short* buf, int stride, int n0, int m0, int lane, f32x16 v){
  const int nn = n0 + (lane & 31), hh = (lane >> 5) << 2;
  #pragma unroll
  for (int q = 0; q < 4; ++q) {
    ushort4v pv;
    #pragma unroll
    for (int s = 0; s < 4; ++s) pv[s] = f2bf(v[4*q + s]);
    *(ushort4v*)&buf[nn * stride + m0 + 8*q + hh] = pv;
  }
}
__device__ __forceinline__ f32x16 ldq(const unsigned short* buf, int stride, int n0, int m0, int lane){
  f32x16 a;
  const int nn = n0 + (lane & 31), hh = (lane >> 5) << 2;
  #pragma unroll
  for (int q = 0; q < 4; ++q) {
    ushort4v pv = *(const ushort4v*)&buf[nn * stride + m0 + 8*q + hh];
    #pragma unroll
    for (int s = 0; s < 4; ++s) a[4*q + s] = bf2f(pv[s]);
  }
  return a;
}
__device__ __forceinline__ f32x16 pinit(const unsigned short* lo, const unsigned short* hi,
                                        int nt, int m0, int lane){
  const unsigned short* base = (nt ? hi : lo) + (lane & 31) * S64;
  const int hh = (lane >> 5) << 2;
  f32x16 p;
  #pragma unroll
  for (int q = 0; q < 4; ++q) {
    ushort4v t = *(const ushort4v*)&base[m0 + 8*q + hh];
    #pragma unroll
    for (int s = 0; s < 4; ++s) p[4*q + s] = bf2f(t[s]);
  }
  return p;
}
#define BAR() do { asm volatile("s_waitcnt lgkmcnt(0)" ::: "memory"); __builtin_amdgcn_s_barrier(); } while(0)

// ---------------- workspace layout (ushort units per (head,chunk) record) ----------------
#define REC  36864
#define QOFF 0
#define WOFF 8192     // W' row-major [64 tok][128 dk]
#define UOFF 16384    // U^T row-major [128 v][64 tok]
#define KOFF 24576    // KST row-major [128 dk][64 tok]
#define MOFF 32768    // M row-major [64 out-tok][64 src-tok]

// ================================ K1: per-chunk operators (512 thr) ================================
#define AOF 0
#define BOF 9216
#define XS0 17920
#define XS1 22528
#define XS2 27136
#define XS3 31744
#define MRO 36352

__global__ __launch_bounds__(512, 4)
void gdn_prep(const float* __restrict__ Qg, const float* __restrict__ Kg,
              const float* __restrict__ Vg, const float* __restrict__ Gg,
              const float* __restrict__ Bg,
              unsigned short* __restrict__ wsp, float* __restrict__ wcs)
{
  __shared__ unsigned short a[40448];
  __shared__ float s_swv[64], s_swiv[64], s_sbe[64];

  const int tid = threadIdx.x, w = tid >> 6, lane = tid & 63;
  const int mt = (w & 3) >> 1, nt = w & 1;
  const int hc = blockIdx.x, head = hc >> 5, c = hc & 31;
  const int t0 = c * CC;
  const size_t rb = (size_t)head * SEQL * DD + (size_t)t0 * DD;
  const float* kp = Kg + rb;
  const float* qp = Qg + rb;
  const float* vp = Vg + rb;
  const float* gp = Gg + (size_t)head * SEQL + t0;
  const float* bp = Bg + (size_t)head * SEQL + t0;
  unsigned short* rec = wsp + (size_t)hc * REC;

  const int lrow = tid >> 3;
  const int c16  = (tid & 7) * 16;
  const int c8p  = (tid & 7) * 8;

  // ---- ph01: load K/Q, scan g, normalize, stage K~/Q~ (+Q~ -> ws) ----
  f32x4 kr[4], qr[4];
  #pragma unroll
  for (int i = 0; i < 4; ++i) {
    kr[i] = *(const f32x4*)(kp + (size_t)lrow * DD + c16 + 4*i);
    qr[i] = *(const f32x4*)(qp + (size_t)lrow * DD + c16 + 4*i);
  }
  float gl = gp[lane], bl = bp[lane];
  float sc = gl;
  #pragma unroll
  for (int d = 1; d < 64; d <<= 1) { float t = __shfl_up(sc, d); if (lane >= d) sc += t; }
  float wv = __expf(sc);
  if (w == 0) { s_swv[lane] = wv; s_swiv[lane] = __expf(-sc); s_sbe[lane] = bl; }
  float ssk = 0.f, ssq = 0.f;
  #pragma unroll
  for (int i = 0; i < 4; ++i) {
    ssk += kr[i][0]*kr[i][0] + kr[i][1]*kr[i][1] + kr[i][2]*kr[i][2] + kr[i][3]*kr[i][3];
    ssq += qr[i][0]*qr[i][0] + qr[i][1]*qr[i][1] + qr[i][2]*qr[i][2] + qr[i][3]*qr[i][3];
  }
  ssk += __shfl_xor(ssk, 1); ssk += __shfl_xor(ssk, 2); ssk += __shfl_xor(ssk, 4);
  ssq += __shfl_xor(ssq, 1); ssq += __shfl_xor(ssq, 2); ssq += __shfl_xor(ssq, 4);
  const float ik = 1.f / fmaxf(sqrtf(ssk), 1e-6f);
  const float wl = __shfl(wv, lrow);
  const float iq = 0.08838834764831845f / fmaxf(sqrtf(ssq), 1e-6f) * wl;
  #pragma unroll
  for (int i = 0; i < 4; ++i) {
    ushort4v pk, pq;
    #pragma unroll
    for (int r = 0; r < 4; ++r) { pk[r] = f2bf(kr[i][r]*ik); pq[r] = f2bf(qr[i][r]*iq); }
    *(ushort4v*)&a[AOF + lrow*SK + c16 + 4*i] = pk;
    *(ushort4v*)&a[BOF + lrow*SK + c16 + 4*i] = pq;
    *(ushort4v*)(rec + QOFF + lrow*DD + c16 + 4*i) = pq;
  }
  BAR();

  // ---- ph2 (8 jobs): w<4: KK^T -> X0,X0T ; w>=4: KQ~ -> M direct to ws ----
  if (w < 4) {
    f32x16 ckk = gemm32<8>(a+AOF, SK, 32*mt, a+AOF, SK, 32*nt, z16(), lane);
    const int nn = 32*nt + (lane & 31), hh = (lane >> 5) << 2;
    const float ben = s_sbe[nn], wvn = s_swv[nn], sin = s_swiv[nn];
    #pragma unroll
    for (int q = 0; q < 4; ++q) {
      ushort4v xT, xR;
      #pragma unroll
      for (int si = 0; si < 4; ++si) {
        const int r = 4*q + si, mm = 32*mt + 8*q + hh + si;
        const float svm = s_swv[mm], sim = s_swiv[mm], bem = s_sbe[mm];
        xT[si] = (mm > nn) ? f2bf(bem*svm*sin*ckk[r]) : 0;
        xR[si] = (nn > mm) ? f2bf(ben*wvn*sim*ckk[r]) : 0;
      }
      const int off = nn*S64 + 32*mt + 8*q + hh;
      *(ushort4v*)&a[XS1 + off] = xT;
      *(ushort4v*)&a[XS0 + off] = xR;
    }
  } else {
    f32x16 ckq = gemm32<8>(a+AOF, SK, 32*mt, a+BOF, SK, 32*nt, z16(), lane);
    const int nn = 32*nt + (lane & 31), hh = (lane >> 5) << 2;
    #pragma unroll
    for (int q = 0; q < 4; ++q) {
      ushort4v mv;
      #pragma unroll
      for (int si = 0; si < 4; ++si) {
        const int r = 4*q + si, mm = 32*mt + 8*q + hh + si;
        mv[si] = (mm <= nn) ? f2bf(ckq[r]*s_swiv[mm]) : 0;
      }
      *(ushort4v*)(rec + MOFF + nn*64 + 32*mt + 8*q + hh) = mv;
    }
  }
  BAR();

  // ---- ph3: X1 = X0^2 dual ; P0 = I - X0 ; issue V loads ----
  f32x4 vr[4];
  #pragma unroll
  for (int i = 0; i < 4; ++i)
    vr[i] = *(const f32x4*)(vp + (size_t)lrow * DD + c16 + 4*i);
  if (w < 4) {
    f32x16 c1 = gemm32<4>(a+XS0, S64, 32*mt, a+XS1, S64, 32*nt, z16(), lane);
    stq(a+XS3, S64, 32*nt, 32*mt, lane, c1);
  } else {
    f32x16 c2 = gemm32<4>(a+XS1, S64, 32*mt, a+XS0, S64, 32*nt, z16(), lane);
    stq(a+XS2, S64, 32*nt, 32*mt, lane, c2);
  }
  {
    unsigned short* p0 = a + ((lrow < 32) ? BOF : BOF+2304) + (lrow & 31)*S64;
    const unsigned short* x0 = a + XS0 + lrow*S64;
    short8 xv = *(const short8*)&x0[c8p];
    short8 ov;
    #pragma unroll
    for (int e = 0; e < 8; ++e) {
      const int col = c8p + e;
      ov[e] = (short)f2bf(((col == lrow) ? 1.f : 0.f) - bf2f((unsigned short)xv[e]));
    }
    *(short8*)&p0[c8p] = ov;
  }
  BAR();

  // ---- ph4 (lev0): X2 dual + P1 ----
  if (w < 4) {
    f32x16 c1 = gemm32<4>(a+XS2, S64, 32*mt, a+XS3, S64, 32*nt, z16(), lane);
    stq(a+XS1, S64, 32*nt, 32*mt, lane, c1);
    f32x16 p = pinit(a+BOF, a+BOF+2304, nt, 32*mt, lane);
    p = gemm32<4>(a+XS3, S64, 32*mt, (nt ? a+BOF+2304 : a+BOF), S64, 0, p, lane);
    stq((nt ? a+MRO : a+BOF+SLOT), S64, 0, 32*mt, lane, p);
  } else {
    f32x16 c2 = gemm32<4>(a+XS3, S64, 32*mt, a+XS2, S64, 32*nt, z16(), lane);
    stq(a+XS0, S64, 32*nt, 32*mt, lane, c2);
  }
  BAR();

  // ---- ph5 (lev1): A^8 + P2 ----
  if (w < 4) {
    f32x16 c1 = gemm32<4>(a+XS0, S64, 32*mt, a+XS1, S64, 32*nt, z16(), lane);
    stq(a+XS2, S64, 32*nt, 32*mt, lane, c1);   // A^8 rm
  } else {
    f32x16 p = pinit(a+BOF+SLOT, a+MRO, nt, 32*mt, lane);
    p = gemm32<4>(a+XS1, S64, 32*mt, (nt ? a+MRO : a+BOF+SLOT), S64, 0, p, lane);
    stq((nt ? a+BOF+2304 : a+BOF), S64, 0, 32*mt, lane, p);
  }
  BAR();

  // ---- ph6: T = P2 + A^8*P2 ; VT scatter ----
  if (w < 4) {
    f32x16 p = pinit(a+BOF, a+BOF+2304, nt, 32*mt, lane);
    p = gemm32<4>(a+XS2, S64, 32*mt, (nt ? a+BOF+2304 : a+BOF), S64, 0, p, lane);
    stq((nt ? a+MRO : a+BOF+SLOT), S64, 0, 32*mt, lane, p);
  }
  #pragma unroll
  for (int i = 0; i < 4; ++i)
    #pragma unroll
    for (int r = 0; r < 4; ++r)
      a[XS0 + (c16 + 4*i + r)*S64 + lrow] = f2bf(vr[i][r]);
  BAR();

  // ---- ph7: T2/T3 elementwise ; KT identity -> XS2..XS3 ; KST -> ws ----
  {
    unsigned short* trow  = a + ((lrow < 32) ? BOF+SLOT : MRO) + (lrow & 31)*S64;
    unsigned short* t3row = a + ((lrow < 32) ? BOF : BOF+2304) + (lrow & 31)*S64;
    short8 tv = *(const short8*)&trow[c8p];
    short8 o2, o3;
    #pragma unroll
    for (int e = 0; e < 8; ++e) {
      const int j = c8p + e;
      const float t = bf2f((unsigned short)tv[e]);
      o2[e] = (short)f2bf(-t * s_sbe[j] * s_swv[j]);
      o3[e] = (short)f2bf( t * s_sbe[j]);
    }
    *(short8*)&trow[c8p]  = o2;   // T2
    *(short8*)&t3row[c8p] = o3;   // T3
  }
  {
    const int j = w >> 2, d4 = w & 3;
    const float wcv = s_swv[63];
    f32x16 ckt = z16();
    #pragma unroll
    for (int kk = 0; kk < 2; ++kk) {
      const int kt = 2*d4 + kk;
      ckt = MM32(frg(a+AOF, SK, 32*j, kt, lane), ifrag(32*d4, kt, lane), ckt);
    }
    stq(a+XS2, S64, 32*d4, 32*j, lane, ckt);
    const int nn = 32*d4 + (lane & 31), hh = (lane >> 5) << 2;
    #pragma unroll
    for (int q = 0; q < 4; ++q) {
      ushort4v o;
      #pragma unroll
      for (int si = 0; si < 4; ++si) {
        const int tok = 32*j + 8*q + hh + si;
        o[si] = f2bf(ckt[4*q+si] * wcv * s_swiv[tok]);
      }
      *(ushort4v*)(rec + KOFF + nn*64 + 32*j + 8*q + hh) = o;
    }
  }
  BAR();

  // ---- ph8: W' -> ws ; U^T -> ws ; wc ----
  {
    const int j = w >> 2, d4 = w & 3;
    const int nn = lane & 31, hh = (lane >> 5) << 2;
    f32x16 cw = gemm32<4>(a+XS2, S64, 32*d4, (j ? a+MRO : a+BOF+SLOT), S64, 0, z16(), lane);
    #pragma unroll
    for (int q = 0; q < 4; ++q) {
      ushort4v pw;
      #pragma unroll
      for (int si = 0; si < 4; ++si) pw[si] = f2bf(cw[4*q+si]);
      *(ushort4v*)(rec + WOFF + (32*j + nn)*128 + 32*d4 + 8*q + hh) = pw;
    }
    f32x16 cu = gemm32<4>((j ? a+BOF+2304 : a+BOF), S64, 0, a+XS0, S64, 32*d4, z16(), lane);
    #pragma unroll
    for (int q = 0; q < 4; ++q) {
      ushort4v pu;
      #pragma unroll
      for (int si = 0; si < 4; ++si) pu[si] = f2bf(cu[4*q+si]);
      *(ushort4v*)(rec + UOFF + (32*d4 + nn)*64 + 32*j + 8*q + hh) = pu;
    }
    if (tid == 0) wcs[hc] = s_swv[63];
  }
}

// ================================ K2: sequential state scan (R7-verified LDS-staged) ================================
#define OW0  0
#define OW1  8704
#define OK0  17408
#define OK1  26624
#define OU0  35840
#define OU1  40448
#define OM0  45056
#define OM1  49664
#define OS0  54272
#define OS1  62976
#define ODT  71680

__global__ __launch_bounds__(512, 1)
void gdn_scan(const unsigned short* __restrict__ wsp, const float* __restrict__ wcs,
              float* __restrict__ Out, float* __restrict__ FS)
{
  __shared__ unsigned short a[76288];

  const int tid = threadIdx.x, w = tid >> 6, lane = tid & 63;
  const int head = blockIdx.x % NH, vh = blockIdx.x / NH;   // (head,0)/(head,1) on same XCD
  const unsigned short* recs = wsp + (size_t)head * NCH * REC;
  const float* wcsh = wcs + head * NCH;
  float* op = Out + (size_t)head * SEQL * DD + vh * 64;

  const int mtS = w >> 1, ntS = w & 1;     // dk-tile / v-col-tile
  const bool outw = (w < 4);               // out tile (mtS, ntS) for mtS in {0,1}

  f32x16 s = z16();

  const int wr = tid >> 3, wc16 = (tid & 7) * 16;
  const int kr = tid >> 2, kc16 = (tid & 3) * 16;
  const int ur = tid >> 3, uc8 = (tid & 7) * 8;

  short8 stW0, stW1, stK0, stK1, stU, stM, qb[8];
  float wcn = 0.f;

  auto issue = [&](int c){
    const unsigned short* rec = recs + (size_t)c * REC;
    stW0 = *(const short8*)(rec + WOFF + wr*128 + wc16);
    stW1 = *(const short8*)(rec + WOFF + wr*128 + wc16 + 8);
    stK0 = *(const short8*)(rec + KOFF + kr*64 + kc16);
    stK1 = *(const short8*)(rec + KOFF + kr*64 + kc16 + 8);
    stU  = *(const short8*)(rec + UOFF + (vh*64 + ur)*64 + uc8);
    stM  = *(const short8*)(rec + MOFF + ur*64 + uc8);
    if (outw) {
      #pragma unroll
      for (int kt = 0; kt < 8; ++kt)
        qb[kt] = *(const short8*)(rec + QOFF + (32*mtS + (lane & 31))*DD + kt*16 + ((lane >> 5) << 3));
    }
    wcn = wcsh[c];
  };
  auto dswrite = [&](int par){
    unsigned short* bw = a + (par ? OW1 : OW0);
    *(short8*)&bw[wr*SK + wc16]     = stW0;
    *(short8*)&bw[wr*SK + wc16 + 8] = stW1;
    unsigned short* bk = a + (par ? OK1 : OK0);
    *(short8*)&bk[kr*SU + kc16]     = stK0;
    *(short8*)&bk[kr*SU + kc16 + 8] = stK1;
    unsigned short* bu = a + (par ? OU1 : OU0);
    *(short8*)&bu[ur*SU + uc8] = stU;
    unsigned short* bm = a + (par ? OM1 : OM0);
    *(short8*)&bm[ur*SU + uc8] = stM;
  };

  issue(0);
  float wc_cur = wcn;
  dswrite(0);
  stq(a+OS0, SK, 32*ntS, 32*mtS, lane, s);   // S0 = 0
  BAR();

  for (int c = 0; c < NCH; ++c) {
    const int cur = c & 1;
    const unsigned short* W_ = a + (cur ? OW1 : OW0);
    const unsigned short* K_ = a + (cur ? OK1 : OK0);
    const unsigned short* U_ = a + (cur ? OU1 : OU0);
    const unsigned short* M_ = a + (cur ? OM1 : OM0);
    const unsigned short* S_ = a + (cur ? OS1 : OS0);
    unsigned short* Sn       = a + (cur ? OS0 : OS1);

    // Oq = Q~ . S0
    f32x16 oq = z16();
    if (outw) {
      #pragma unroll
      for (int kt = 0; kt < 8; ++kt)
        oq = MM32(qb[kt], frg(S_, SK, 32*ntS, kt, lane), oq);
    }
    if (c < NCH-1) issue(c+1);

    // Delta = U + W' . S0 (per-wave redundant for its v-col), -> ΔT scratch
    {
      f32x16 d0 = gemm32<8>(W_, SK, 0,  S_, SK, 32*ntS, z16(), lane);
      f32x16 d1 = gemm32<8>(W_, SK, 32, S_, SK, 32*ntS, z16(), lane);
      const int nn = 32*ntS + (lane & 31), hh = (lane >> 5) << 2;
      #pragma unroll
      for (int q = 0; q < 4; ++q) {
        ushort4v u0 = *(const ushort4v*)&U_[nn*SU + 0  + 8*q + hh];
        ushort4v u1 = *(const ushort4v*)&U_[nn*SU + 32 + 8*q + hh];
        ushort4v p0, p1;
        #pragma unroll
        for (int si = 0; si < 4; ++si) {
          p0[si] = f2bf(d0[4*q+si] + bf2f(u0[si]));
          p1[si] = f2bf(d1[4*q+si] + bf2f(u1[si]));
        }
        *(ushort4v*)&a[ODT + nn*SU + 0  + 8*q + hh] = p0;
        *(ushort4v*)&a[ODT + nn*SU + 32 + 8*q + hh] = p1;
      }
    }

    // S = wc*S + KST . Delta
    {
      f32x16 sa;
      #pragma unroll
      for (int r = 0; r < 16; ++r) sa[r] = s[r] * wc_cur;
      s = gemm32<4>(K_, SU, 32*mtS, a+ODT, SU, 32*ntS, sa, lane);
    }

    // out = Oq + M . Delta -> global
    if (outw) {
      f32x16 o = gemm32<4>(M_, SU, 32*mtS, a+ODT, SU, 32*ntS, oq, lane);
      const int vv = 32*ntS + (lane & 31), hh = (lane >> 5) << 2;
      float* ob = op + (size_t)(c*CC + 32*mtS) * DD + vv;
      #pragma unroll
      for (int q = 0; q < 4; ++q)
        #pragma unroll
        for (int si = 0; si < 4; ++si)
          ob[(size_t)(si + 8*q + hh) * DD] = o[4*q + si];
    }

    stq(Sn, SK, 32*ntS, 32*mtS, lane, s);
    if (c < NCH-1) dswrite(cur ^ 1);
    wc_cur = wcn;
    BAR();
  }

  // final state
  {
    float* fsp = FS + (size_t)head * DD * DD + vh * 64;
    const int nn = 32*ntS + (lane & 31), hh = (lane >> 5) << 2;
    #pragma unroll
    for (int q = 0; q < 4; ++q)
      #pragma unroll
      for (int si = 0; si < 4; ++si)
        fsp[(size_t)(32*mtS + si + 8*q + hh) * DD + nn] = s[4*q + si];
  }
}

// ================================ fallback (R3, verified) ================================
__global__ __launch_bounds__(512, 1)
void gdn_chunk2(const float* __restrict__ Qg, const float* __restrict__ Kg,
                const float* __restrict__ Vg, const float* __restrict__ Gg,
                const float* __restrict__ Bg,
                float* __restrict__ Out, float* __restrict__ FS)
{
  __shared__ __align__(16) unsigned short sKc[64*SK];
  __shared__ __align__(16) unsigned short sQc[64*SK];
  __shared__ __align__(16) unsigned short sS0T[64*SK];
  __shared__ __align__(16) unsigned short sVc[64*S64];
  __shared__ __align__(16) unsigned short sVT[64*S64];
  __shared__ __align__(16) unsigned short sM[64*S64];
  __shared__ __align__(16) unsigned short sAr[8*SLOT];
  __shared__ float sbe2[2][64], swv2[2][64], swiv2[2][64];

  const int tid  = threadIdx.x;
  const int w    = tid >> 6;
  const int lane = tid & 63;
  const int half = w >> 2;
  const int j    = w & 3;
  const int mt   = j >> 1, nt = j & 1;
  const int mtS  = w >> 1, ntS = w & 1;
  const int mtK  = w >> 2, ntK = w & 3;
  const int head = blockIdx.x % NH;
  const int vh   = blockIdx.x / NH;

  const size_t rb = (size_t)head * SEQL * DD;
  const float* qp = Qg + rb;
  const float* kp = Kg + rb;
  const float* vp = Vg + rb + vh * 64;
  const float* gp = Gg + (size_t)head * SEQL;
  const float* bp = Bg + (size_t)head * SEQL;
  float* op  = Out + rb + vh * 64;
  float* fsp = FS + (size_t)head * DD * DD + vh * 64;

  const int lrow = tid >> 3;
  const int c16  = (tid & 7) * 16;
  const int c8   = (tid & 7) * 8;

  unsigned short* const sl0 = sAr + 0*SLOT;
  unsigned short* const sl1 = sAr + 1*SLOT;
  unsigned short* const sl2 = sAr + 2*SLOT;
  unsigned short* const sl3 = sAr + 3*SLOT;
  unsigned short* const sl4 = sAr + 4*SLOT;
  unsigned short* const sl5 = sAr + 5*SLOT;
  unsigned short* const sl6 = sAr + 6*SLOT;
  unsigned short* const sl7 = sAr + 7*SLOT;

  f32x16 s = z16(), oacc = z16();
  f32x4 kr[4], qr[4], vr[2]; float gr = 0.f, br = 0.f;

  auto prefetch = [&](int t0p){
    const float* kb = kp + (size_t)(t0p + lrow) * DD + c16;
    const float* qb = qp + (size_t)(t0p + lrow) * DD + c16;
    const float* vb = vp + (size_t)(t0p + lrow) * DD + c8;
    #pragma unroll
    for (int i = 0; i < 4; ++i) { kr[i] = *(const f32x4*)(kb + 4*i); qr[i] = *(const f32x4*)(qb + 4*i); }
    #pragma unroll
    for (int i = 0; i < 2; ++i) vr[i] = *(const f32x4*)(vb + 4*i);
    if (w == 7) { gr = gp[t0p + lane]; br = bp[t0p + lane]; }
  };
  auto scan_to = [&](int p){
    if (w == 7) {
      float sc = gr;
      #pragma unroll
      for (int d = 1; d < 64; d <<= 1) { float t = __shfl_up(sc, d); if (lane >= d) sc += t; }
      swv2[p][lane]  = __expf(sc);
      swiv2[p][lane] = __expf(-sc);
      sbe2[p][lane]  = br;
    }
  };

  prefetch(0);
  scan_to(0);
  BAR();

  for (int tc = 0; tc < NCH; ++tc) {
    const int t0 = tc * CC;
    const int cur = tc & 1, nxt = cur ^ 1;
    {
      float ssk = 0.f, ssq = 0.f;
      #pragma unroll
      for (int i = 0; i < 4; ++i) {
        ssk += kr[i][0]*kr[i][0] + kr[i][1]*kr[i][1] + kr[i][2]*kr[i][2] + kr[i][3]*kr[i][3];
        ssq += qr[i][0]*qr[i][0] + qr[i][1]*qr[i][1] + qr[i][2]*qr[i][2] + qr[i][3]*qr[i][3];
      }
      ssk += __shfl_xor(ssk, 1); ssk += __shfl_xor(ssk, 2); ssk += __shfl_xor(ssk, 4);
      ssq += __shfl_xor(ssq, 1); ssq += __shfl_xor(ssq, 2); ssq += __shfl_xor(ssq, 4);
      const float ik = 1.f / fmaxf(sqrtf(ssk), 1e-6f);
      const float iq = 0.08838834764831845f / fmaxf(sqrtf(ssq), 1e-6f) * swv2[cur][lrow];
      #pragma unroll
      for (int i = 0; i < 4; ++i) {
        ushort4v pk, pq;
        #pragma unroll
        for (int r = 0; r < 4; ++r) { pk[r] = f2bf(kr[i][r] * ik); pq[r] = f2bf(qr[i][r] * iq); }
        *(ushort4v*)&sKc[lrow*SK + c16 + 4*i] = pk;
        *(ushort4v*)&sQc[lrow*SK + c16 + 4*i] = pq;
      }
      #pragma unroll
      for (int i = 0; i < 2; ++i) {
        ushort4v pv;
        #pragma unroll
        for (int r = 0; r < 4; ++r) pv[r] = f2bf(vr[i][r]);
        *(ushort4v*)&sVc[lrow*S64 + c8 + 4*i] = pv;
      }
    }
    stq(sS0T, SK, 32*ntS, 32*mtS, lane, s);
    prefetch(tc < NCH-1 ? (tc+1)*CC : t0);
    BAR();

    if (half == 0) {
      f32x16 aa = gemm32<8>(sKc, SK, 32*mt, sKc, SK, 32*nt, z16(), lane);
      const int nn = 32*nt + (lane & 31), hh = (lane >> 5) << 2;
      #pragma unroll
      for (int q = 0; q < 4; ++q) {
        ushort4v pR, pL, pPT, pP;
        #pragma unroll
        for (int si = 0; si < 4; ++si) {
          const int r = 4*q + si, mm = 32*mt + 8*q + hh + si;
          const float S = aa[r];
          const float av  = (mm > nn) ? sbe2[cur][mm]*swv2[cur][mm]*swiv2[cur][nn]*S : 0.f;
          const float atr = (nn > mm) ? sbe2[cur][nn]*swv2[cur][nn]*swiv2[cur][mm]*S : 0.f;
          pR[si]  = f2bf(av);
          pL[si]  = f2bf(atr);
          pPT[si] = f2bf(((mm==nn)?1.f:0.f) - av);
          pP[si]  = f2bf(((mm==nn)?1.f:0.f) - atr);
        }
        const int off = nn*S64 + 32*mt + 8*q + hh;
        *(ushort4v*)&sl1[off] = pR;
        *(ushort4v*)&sl0[off] = pL;
        *(ushort4v*)&sl5[off] = pPT;
        *(ushort4v*)&sl4[off] = pP;
      }
    } else {
      f32x16 aa = gemm32<8>(sKc, SK, 32*mt, sQc, SK, 32*nt, z16(), lane);
      const int nn = 32*nt + (lane & 31), hh = (lane >> 5) << 2;
      #pragma unroll
      for (int q = 0; q < 4; ++q) {
        ushort4v pv;
        #pragma unroll
        for (int si = 0; si < 4; ++si) {
          const int r = 4*q + si, mm = 32*mt + 8*q + hh + si;
          pv[si] = f2bf((mm <= nn) ? aa[r]*swiv2[cur][mm] : 0.f);
        }
        *(ushort4v*)&sM[nn*S64 + 32*mt + 8*q + hh] = pv;
      }
    }
    BAR();

    if (half == 0) {
      f32x16 aa = gemm32<4>(sl0, S64, 32*mt, sl1, S64, 32*nt, z16(), lane);
      stq(sl3, S64, 32*nt, 32*mt, lane, aa);
      f32x16 bb = z16();
      #pragma unroll
      for (int kk = 0; kk < 2; ++kk) {
        const int kt = 2*nt + kk;
        bb = MM32(frg(sVc, S64, 32*mt, kt, lane), ifrag(32*nt, kt, lane), bb);
      }
      stq(sVT, S64, 32*nt, 32*mt, lane, bb);
    } else {
      f32x16 aa = gemm32<4>(sl1, S64, 32*mt, sl0, S64, 32*nt, z16(), lane);
      stq(sl2, S64, 32*nt, 32*mt, lane, aa);
      oacc = gemm32<8>(sQc, SK, 32*mt, sS0T, SK, 32*nt, z16(), lane);
    }
    BAR();

    {
      unsigned short* const inL[3]   = { sl2, sl0, sl2 };
      unsigned short* const inR[3]   = { sl3, sl1, sl3 };
      unsigned short* const outL[3]  = { sl0, sl2, sl0 };
      unsigned short* const outR[3]  = { sl1, sl3, sl1 };
      unsigned short* const inP[3]   = { sl4, sl7, sl5 };
      unsigned short* const inPT[3]  = { sl5, sl6, sl4 };
      unsigned short* const outP[3]  = { sl7, sl5, sl7 };
      unsigned short* const outPT[3] = { sl6, sl4, sl6 };
      #pragma unroll
      for (int lev = 0; lev < 3; ++lev) {
        if (half == 0) {
          f32x16 aa = gemm32<4>(inL[lev], S64, 32*mt, inR[lev], S64, 32*nt, z16(), lane);
          stq(outR[lev], S64, 32*nt, 32*mt, lane, aa);
          f32x16 p = ldq(inPT[lev], S64, 32*nt, 32*mt, lane);
          p = gemm32<4>(inP[lev], S64, 32*mt, inR[lev], S64, 32*nt, p, lane);
          stq(outPT[lev], S64, 32*nt, 32*mt, lane, p);
        } else {
          f32x16 aa = gemm32<4>(inR[lev], S64, 32*mt, inL[lev], S64, 32*nt, z16(), lane);
          stq(outL[lev], S64, 32*nt, 32*mt, lane, aa);
          f32x16 p = ldq(inP[lev], S64, 32*nt, 32*mt, lane);
          p = gemm32<4>(inR[lev], S64, 32*mt, inP[lev], S64, 32*nt, p, lane);
          stq(outP[lev], S64, 32*nt, 32*mt, lane, p);
        }
        BAR();
      }
    }

    if (half == 0) {
      f32x16 aa = gemm32<4>(sl0, S64, 32*mt, sl1, S64, 32*nt, z16(), lane);
      stq(sl2, S64, 32*nt, 32*mt, lane, aa);
    } else {
      f32x16 p = ldq(sl7, S64, 32*nt, 32*mt, lane);
      p = gemm32<4>(sl1, S64, 32*mt, sl7, S64, 32*nt, p, lane);
      stq(sl4, S64, 32*nt, 32*mt, lane, p);
    }
    BAR();

    if (half == 0) {
      f32x16 p = ldq(sl4, S64, 32*nt, 32*mt, lane);
      p = gemm32<4>(sl2, S64, 32*mt, sl4, S64, 32*nt, p, lane);
      const int nn = 32*nt + (lane & 31), hh = (lane >> 5) << 2;
      #pragma unroll
      for (int q = 0; q < 4; ++q) {
        ushort4v p2, p3;
        #pragma unroll
        for (int si = 0; si < 4; ++si) {
          const int r = 4*q + si, mm = 32*mt + 8*q + hh + si;
          const float t = p[r];
          p2[si] = f2bf(-t * sbe2[cur][mm] * swv2[cur][mm]);
          p3[si] = f2bf( t * sbe2[cur][mm]);
        }
        const int off = nn*S64 + 32*mt + 8*q + hh;
        *(ushort4v*)&sl1[off] = p2;
        *(ushort4v*)&sl5[off] = p3;
      }
    } else {
      f32x16 zz = gemm32<8>(sKc, SK, 32*mt, sS0T, SK, 32*nt, z16(), lane);
      stq(sl0, S64, 32*nt, 32*mt, lane, zz);
    }
    {
      f32x16 aa = z16();
      #pragma unroll
      for (int kk = 0; kk < 2; ++kk) {
        const int kt = 2*ntK + kk;
        aa = MM32(frg(sKc, SK, 32*mtK, kt, lane), ifrag(32*ntK, kt, lane), aa);
      }
      stq(sl6, S64, 32*ntK, 32*mtK, lane, aa);
    }
    BAR();

    if (half == 0) {
      f32x16 d = gemm32<4>(sl5, S64, 32*mt, sVT, S64, 32*nt, z16(), lane);
      d = gemm32<4>(sl1, S64, 32*mt, sl0, S64, 32*nt, d, lane);
      const int nn = 32*nt + (lane & 31), hh = (lane >> 5) << 2;
      const float w63 = swv2[cur][63];
      #pragma unroll
      for (int q = 0; q < 4; ++q) {
        ushort4v pt, ps;
        #pragma unroll
        for (int si = 0; si < 4; ++si) {
          const int r = 4*q + si, mm = 32*mt + 8*q + hh + si;
          pt[si] = f2bf(d[r]);
          ps[si] = f2bf(d[r] * w63 * swiv2[cur][mm]);
        }
        const int off = nn*S64 + 32*mt + 8*q + hh;
        *(ushort4v*)&sl3[off] = pt;
        *(ushort4v*)&sl2[off] = ps;
      }
    }
    scan_to(nxt);
    {
      const float w63 = swv2[cur][63];
      #pragma unroll
      for (int r = 0; r < 16; ++r) s[r] *= w63;
    }
    BAR();

    s = gemm32<4>(sl6, S64, 32*mtS, sl2, S64, 32*ntS, s, lane);
    if (half == 1) {
      f32x16 o = oacc;
      o = gemm32<4>(sM, S64, 32*mt, sl3, S64, 32*nt, o, lane);
      const int nn = 32*nt + (lane & 31), hh = (lane >> 5) << 2;
      #pragma unroll
      for (int q = 0; q < 4; ++q)
        #pragma unroll
        for (int si = 0; si < 4; ++si)
          op[(size_t)(t0 + 32*mt + 8*q + hh + si) * DD + nn] = o[4*q + si];
    }
    BAR();
  }

  {
    const int nn = 32*ntS + (lane & 31), hh = (lane >> 5) << 2;
    #pragma unroll
    for (int q = 0; q < 4; ++q)
      #pragma unroll
      for (int si = 0; si < 4; ++si)
        fsp[(size_t)(32*mtS + 8*q + hh + si) * DD + nn] = s[4*q + si];
  }
}

extern "C" void kernel_launch(void* const* d_in, const int* in_sizes, int n_in,
                              void* d_out, int out_size, void* d_ws, size_t ws_size,
                              hipStream_t stream) {
  const float* Q = (const float*)d_in[0];
  const float* K = (const float*)d_in[1];
  const float* V = (const float*)d_in[2];
  const float* G = (const float*)d_in[3];
  const float* B = (const float*)d_in[4];
  float* Out = (float*)d_out;
  float* FS  = Out + (size_t)NH * SEQL * DD;

  const size_t WS_NEED = (size_t)NH * NCH * REC * 2 + (size_t)NH * NCH * 4;
  if (ws_size >= WS_NEED) {
    unsigned short* wsp = (unsigned short*)d_ws;
    float* wcs = (float*)(wsp + (size_t)NH * NCH * REC);
    hipLaunchKernelGGL(gdn_prep, dim3(NH*NCH), dim3(512), 0, stream, Q, K, V, G, B, wsp, wcs);
    hipLaunchKernelGGL(gdn_scan, dim3(NH*2), dim3(512), 0, stream, wsp, wcs, Out, FS);
  } else {
    hipLaunchKernelGGL(gdn_chunk2, dim3(NH*2), dim3(512), 0, stream, Q, K, V, G, B, Out, FS);
  }
}

// Round 13
// 227.377 us; speedup vs baseline: 1.1910x; 1.0149x over previous
//
#include <hip/hip_runtime.h>
#include <hip/hip_bf16.h>

typedef __attribute__((ext_vector_type(8)))  short short8;
typedef __attribute__((ext_vector_type(4)))  float f32x4;
typedef __attribute__((ext_vector_type(16))) float f32x16;
typedef __attribute__((ext_vector_type(4)))  unsigned short ushort4v;

#define NH   96
#define SEQL 2048
#define DD   128
#define CC   64
#define NCH  32
#define SK   136
#define S64  72
#define SU   72
#define SLOT 4608

__device__ __forceinline__ unsigned short f2bf(float f){
  __hip_bfloat16 h = __float2bfloat16(f);
  union { __hip_bfloat16 h; unsigned short u; } v; v.h = h; return v.u;
}
__device__ __forceinline__ float bf2f(unsigned short u){
  union { unsigned u; float f; } v; v.u = ((unsigned)u) << 16; return v.f;
}
__device__ __forceinline__ short8 frg(const unsigned short* b, int stride, int row0, int kt, int lane){
  return *(const short8*)&b[(row0 + (lane & 31)) * stride + (kt << 4) + ((lane >> 5) << 3)];
}
__device__ __forceinline__ short8 ifrag(int n0, int kt, int lane){
  const int idx = n0 + (lane & 31) - (kt << 4) - ((lane >> 5) << 3);
  short8 v;
  #pragma unroll
  for (int e = 0; e < 8; ++e) v[e] = (short)((e == idx) ? 0x3F80 : 0);
  return v;
}
#define MM32(A,B,C) __builtin_amdgcn_mfma_f32_32x32x16_bf16(A,B,C,0,0,0)
__device__ __forceinline__ f32x16 z16(){
  return (f32x16){0.f,0.f,0.f,0.f,0.f,0.f,0.f,0.f,0.f,0.f,0.f,0.f,0.f,0.f,0.f,0.f};
}
template<int KTN>
__device__ __forceinline__ f32x16 gemm32(const unsigned short* A, int sa, int m0,
                                         const unsigned short* B, int sb, int n0,
                                         f32x16 acc, int lane){
  #pragma unroll
  for (int kt = 0; kt < KTN; ++kt)
    acc = MM32(frg(A, sa, m0, kt, lane), frg(B, sb, n0, kt, lane), acc);
  return acc;
}
// store C^T row-major (bf16)
__device__ __forceinline__ void stq(unsigned short* buf, int stride, int n0, int m0, int lane, f32x16 v){
  const int nn = n0 + (lane & 31), hh = (lane >> 5) << 2;
  #pragma unroll
  for (int q = 0; q < 4; ++q) {
    ushort4v pv;
    #pragma unroll
    for (int s = 0; s < 4; ++s) pv[s] = f2bf(v[4*q + s]);
    *(ushort4v*)&buf[nn * stride + m0 + 8*q + hh] = pv;
  }
}
__device__ __forceinline__ f32x16 ldq(const unsigned short* buf, int stride, int n0, int m0, int lane){
  f32x16 a;
  const int nn = n0 + (lane & 31), hh = (lane >> 5) << 2;
  #pragma unroll
  for (int q = 0; q < 4; ++q) {
    ushort4v pv = *(const ushort4v*)&buf[nn * stride + m0 + 8*q + hh];
    #pragma unroll
    for (int s = 0; s < 4; ++s) a[4*q + s] = bf2f(pv[s]);
  }
  return a;
}
__device__ __forceinline__ f32x16 pinit(const unsigned short* lo, const unsigned short* hi,
                                        int nt, int m0, int lane){
  const unsigned short* base = (nt ? hi : lo) + (lane & 31) * S64;
  const int hh = (lane >> 5) << 2;
  f32x16 p;
  #pragma unroll
  for (int q = 0; q < 4; ++q) {
    ushort4v t = *(const ushort4v*)&base[m0 + 8*q + hh];
    #pragma unroll
    for (int s = 0; s < 4; ++s) p[4*q + s] = bf2f(t[s]);
  }
  return p;
}
#define BAR() do { asm volatile("s_waitcnt lgkmcnt(0)" ::: "memory"); __builtin_amdgcn_s_barrier(); } while(0)

// ---------------- workspace layout (ushort units per (head,chunk) record) ----------------
#define REC  36864
#define QOFF 0
#define WOFF 8192     // W' row-major [64 tok][128 dk]
#define UOFF 16384    // U^T row-major [128 v][64 tok]
#define KOFF 24576    // KST row-major [128 dk][64 tok]
#define MOFF 32768    // M row-major [64 out-tok][64 src-tok]

// ================================ K1: per-chunk operators (512 thr, 7 phases) ================================
#define AOF 0
#define BOF 9216
#define XS0 17920
#define XS1 22528
#define XS2 27136
#define XS3 31744
#define MRO 36352

__global__ __launch_bounds__(512, 4)
void gdn_prep(const float* __restrict__ Qg, const float* __restrict__ Kg,
              const float* __restrict__ Vg, const float* __restrict__ Gg,
              const float* __restrict__ Bg,
              unsigned short* __restrict__ wsp, float* __restrict__ wcs)
{
  __shared__ unsigned short a[40448];
  __shared__ float s_swv[64], s_swiv[64], s_sbe[64];

  const int tid = threadIdx.x, w = tid >> 6, lane = tid & 63;
  const int mt = (w & 3) >> 1, nt = w & 1;
  const int hc = blockIdx.x, head = hc >> 5, c = hc & 31;
  const int t0 = c * CC;
  const size_t rb = (size_t)head * SEQL * DD + (size_t)t0 * DD;
  const float* kp = Kg + rb;
  const float* qp = Qg + rb;
  const float* vp = Vg + rb;
  const float* gp = Gg + (size_t)head * SEQL + t0;
  const float* bp = Bg + (size_t)head * SEQL + t0;
  unsigned short* rec = wsp + (size_t)hc * REC;

  const int lrow = tid >> 3;
  const int c16  = (tid & 7) * 16;
  const int c8p  = (tid & 7) * 8;

  // ---- ph01: load K/Q, scan g, normalize, stage K~/Q~ (+Q~ -> ws) ----
  f32x4 kr[4], qr[4];
  #pragma unroll
  for (int i = 0; i < 4; ++i) {
    kr[i] = *(const f32x4*)(kp + (size_t)lrow * DD + c16 + 4*i);
    qr[i] = *(const f32x4*)(qp + (size_t)lrow * DD + c16 + 4*i);
  }
  float gl = gp[lane], bl = bp[lane];
  float sc = gl;
  #pragma unroll
  for (int d = 1; d < 64; d <<= 1) { float t = __shfl_up(sc, d); if (lane >= d) sc += t; }
  float wv = __expf(sc);
  if (w == 0) { s_swv[lane] = wv; s_swiv[lane] = __expf(-sc); s_sbe[lane] = bl; }
  float ssk = 0.f, ssq = 0.f;
  #pragma unroll
  for (int i = 0; i < 4; ++i) {
    ssk += kr[i][0]*kr[i][0] + kr[i][1]*kr[i][1] + kr[i][2]*kr[i][2] + kr[i][3]*kr[i][3];
    ssq += qr[i][0]*qr[i][0] + qr[i][1]*qr[i][1] + qr[i][2]*qr[i][2] + qr[i][3]*qr[i][3];
  }
  ssk += __shfl_xor(ssk, 1); ssk += __shfl_xor(ssk, 2); ssk += __shfl_xor(ssk, 4);
  ssq += __shfl_xor(ssq, 1); ssq += __shfl_xor(ssq, 2); ssq += __shfl_xor(ssq, 4);
  const float ik = 1.f / fmaxf(sqrtf(ssk), 1e-6f);
  const float wl = __shfl(wv, lrow);
  const float iq = 0.08838834764831845f / fmaxf(sqrtf(ssq), 1e-6f) * wl;
  #pragma unroll
  for (int i = 0; i < 4; ++i) {
    ushort4v pk, pq;
    #pragma unroll
    for (int r = 0; r < 4; ++r) { pk[r] = f2bf(kr[i][r]*ik); pq[r] = f2bf(qr[i][r]*iq); }
    *(ushort4v*)&a[AOF + lrow*SK + c16 + 4*i] = pk;
    *(ushort4v*)&a[BOF + lrow*SK + c16 + 4*i] = pq;
    *(ushort4v*)(rec + QOFF + lrow*DD + c16 + 4*i) = pq;
  }
  BAR();

  // ---- ph2: w<4: KK^T -> A rm @XS0, A^T rm @XS1 ; w>=4: KQ~ -> M direct to ws ----
  if (w < 4) {
    f32x16 ckk = gemm32<8>(a+AOF, SK, 32*mt, a+AOF, SK, 32*nt, z16(), lane);
    const int nn = 32*nt + (lane & 31), hh = (lane >> 5) << 2;
    const float ben = s_sbe[nn], wvn = s_swv[nn], sin = s_swiv[nn];
    #pragma unroll
    for (int q = 0; q < 4; ++q) {
      ushort4v xT, xR;
      #pragma unroll
      for (int si = 0; si < 4; ++si) {
        const int r = 4*q + si, mm = 32*mt + 8*q + hh + si;
        const float svm = s_swv[mm], sim = s_swiv[mm], bem = s_sbe[mm];
        xT[si] = (mm > nn) ? f2bf(bem*svm*sin*ckk[r]) : 0;
        xR[si] = (nn > mm) ? f2bf(ben*wvn*sim*ckk[r]) : 0;
      }
      const int off = nn*S64 + 32*mt + 8*q + hh;
      *(ushort4v*)&a[XS1 + off] = xT;
      *(ushort4v*)&a[XS0 + off] = xR;
    }
  } else {
    f32x16 ckq = gemm32<8>(a+AOF, SK, 32*mt, a+BOF, SK, 32*nt, z16(), lane);
    const int nn = 32*nt + (lane & 31), hh = (lane >> 5) << 2;
    #pragma unroll
    for (int q = 0; q < 4; ++q) {
      ushort4v mv;
      #pragma unroll
      for (int si = 0; si < 4; ++si) {
        const int r = 4*q + si, mm = 32*mt + 8*q + hh + si;
        mv[si] = (mm <= nn) ? f2bf(ckq[r]*s_swiv[mm]) : 0;
      }
      *(ushort4v*)(rec + MOFF + nn*64 + 32*mt + 8*q + hh) = mv;
    }
  }
  BAR();

  // ---- ph3: A^2 dual (XS3 = A2^T, XS2 = A2 rm) ; P0 = I - A ; issue V loads ----
  f32x4 vr[4];
  #pragma unroll
  for (int i = 0; i < 4; ++i)
    vr[i] = *(const f32x4*)(vp + (size_t)lrow * DD + c16 + 4*i);
  if (w < 4) {
    f32x16 c1 = gemm32<4>(a+XS0, S64, 32*mt, a+XS1, S64, 32*nt, z16(), lane);
    stq(a+XS3, S64, 32*nt, 32*mt, lane, c1);
  } else {
    f32x16 c2 = gemm32<4>(a+XS1, S64, 32*mt, a+XS0, S64, 32*nt, z16(), lane);
    stq(a+XS2, S64, 32*nt, 32*mt, lane, c2);
  }
  {
    unsigned short* p0 = a + ((lrow < 32) ? BOF : BOF+2304) + (lrow & 31)*S64;
    const unsigned short* x0 = a + XS0 + lrow*S64;
    short8 xv = *(const short8*)&x0[c8p];
    short8 ov;
    #pragma unroll
    for (int e = 0; e < 8; ++e) {
      const int col = c8p + e;
      ov[e] = (short)f2bf(((col == lrow) ? 1.f : 0.f) - bf2f((unsigned short)xv[e]));
    }
    *(short8*)&p0[c8p] = ov;
  }
  BAR();

  // ---- ph4: w<4: A4^T -> XS1 ; w>=4: P1 = P0 + P0*A2 -> {BOF+SLOT, MRO} ----
  if (w < 4) {
    f32x16 c1 = gemm32<4>(a+XS2, S64, 32*mt, a+XS3, S64, 32*nt, z16(), lane);
    stq(a+XS1, S64, 32*nt, 32*mt, lane, c1);   // A^4T rm
  } else {
    f32x16 p = pinit(a+BOF, a+BOF+2304, nt, 32*mt, lane);
    p = gemm32<4>(a+XS3, S64, 32*mt, (nt ? a+BOF+2304 : a+BOF), S64, 0, p, lane);
    stq((nt ? a+MRO : a+BOF+SLOT), S64, 0, 32*mt, lane, p);   // P1 rm halves
  }
  BAR();

  // ---- ph5': w<4: T = P1 + P1*A4 -> {BOF, BOF+2304} ; all: V^T scatter -> XS2..XS3 ----
  if (w < 4) {
    f32x16 p = pinit(a+BOF+SLOT, a+MRO, nt, 32*mt, lane);
    p = gemm32<4>(a+XS1, S64, 32*mt, (nt ? a+MRO : a+BOF+SLOT), S64, 0, p, lane);
    stq((nt ? a+BOF+2304 : a+BOF), S64, 0, 32*mt, lane, p);   // T rm halves
  }
  #pragma unroll
  for (int i = 0; i < 4; ++i)
    #pragma unroll
    for (int r = 0; r < 4; ++r)
      a[XS2 + (c16 + 4*i + r)*S64 + lrow] = f2bf(vr[i][r]);    // VT [128][72] over XS2..XS3
  BAR();

  // ---- ph6': T2/T3 elementwise ; KT identity -> XS0..XS1 ; KST -> ws ----
  {
    unsigned short* trow  = a + ((lrow < 32) ? BOF : BOF+2304) + (lrow & 31)*S64;
    unsigned short* t3row = a + ((lrow < 32) ? BOF+SLOT : MRO) + (lrow & 31)*S64;
    short8 tv = *(const short8*)&trow[c8p];
    short8 o2, o3;
    #pragma unroll
    for (int e = 0; e < 8; ++e) {
      const int j = c8p + e;
      const float t = bf2f((unsigned short)tv[e]);
      o2[e] = (short)f2bf(-t * s_sbe[j] * s_swv[j]);
      o3[e] = (short)f2bf( t * s_sbe[j]);
    }
    *(short8*)&trow[c8p]  = o2;   // T2 in place ({BOF, BOF+2304})
    *(short8*)&t3row[c8p] = o3;   // T3 -> {BOF+SLOT, MRO}
  }
  {
    const int j = w >> 2, d4 = w & 3;
    const float wcv = s_swv[63];
    f32x16 ckt = z16();
    #pragma unroll
    for (int kk = 0; kk < 2; ++kk) {
      const int kt = 2*d4 + kk;
      ckt = MM32(frg(a+AOF, SK, 32*j, kt, lane), ifrag(32*d4, kt, lane), ckt);
    }
    stq(a+XS0, S64, 32*d4, 32*j, lane, ckt);   // KT [128][72] over XS0..XS1
    const int nn = 32*d4 + (lane & 31), hh = (lane >> 5) << 2;
    #pragma unroll
    for (int q = 0; q < 4; ++q) {
      ushort4v o;
      #pragma unroll
      for (int si = 0; si < 4; ++si) {
        const int tok = 32*j + 8*q + hh + si;
        o[si] = f2bf(ckt[4*q+si] * wcv * s_swiv[tok]);
      }
      *(ushort4v*)(rec + KOFF + nn*64 + 32*j + 8*q + hh) = o;
    }
  }
  BAR();

  // ---- ph7': W' -> ws ; U^T -> ws ; wc ----
  {
    const int j = w >> 2, d4 = w & 3;
    const int nn = lane & 31, hh = (lane >> 5) << 2;
    // W'T tile: KT(XS0..XS1) . T2half^T ; T2 halves at {BOF (j=0), BOF+2304 (j=1)}
    f32x16 cw = gemm32<4>(a+XS0, S64, 32*d4, (j ? a+BOF+2304 : a+BOF), S64, 0, z16(), lane);
    #pragma unroll
    for (int q = 0; q < 4; ++q) {
      ushort4v pw;
      #pragma unroll
      for (int si = 0; si < 4; ++si) pw[si] = f2bf(cw[4*q+si]);
      *(ushort4v*)(rec + WOFF + (32*j + nn)*128 + 32*d4 + 8*q + hh) = pw;
    }
    // U^T tile: T3half . VT(XS2..XS3) ; T3 halves at {BOF+SLOT (j=0), MRO (j=1)}
    f32x16 cu = gemm32<4>((j ? a+MRO : a+BOF+SLOT), S64, 0, a+XS2, S64, 32*d4, z16(), lane);
    #pragma unroll
    for (int q = 0; q < 4; ++q) {
      ushort4v pu;
      #pragma unroll
      for (int si = 0; si < 4; ++si) pu[si] = f2bf(cu[4*q+si]);
      *(ushort4v*)(rec + UOFF + (32*d4 + nn)*64 + 32*j + 8*q + hh) = pu;
    }
    if (tid == 0) wcs[hc] = s_swv[63];
  }
}

// ================================ K2: sequential state scan (R7/R12-verified LDS-staged) ================================
#define OW0  0
#define OW1  8704
#define OK0  17408
#define OK1  26624
#define OU0  35840
#define OU1  40448
#define OM0  45056
#define OM1  49664
#define OS0  54272
#define OS1  62976
#define ODT  71680

__global__ __launch_bounds__(512, 1)
void gdn_scan(const unsigned short* __restrict__ wsp, const float* __restrict__ wcs,
              float* __restrict__ Out, float* __restrict__ FS)
{
  __shared__ unsigned short a[76288];

  const int tid = threadIdx.x, w = tid >> 6, lane = tid & 63;
  const int head = blockIdx.x % NH, vh = blockIdx.x / NH;   // (head,0)/(head,1) on same XCD
  const unsigned short* recs = wsp + (size_t)head * NCH * REC;
  const float* wcsh = wcs + head * NCH;
  float* op = Out + (size_t)head * SEQL * DD + vh * 64;

  const int mtS = w >> 1, ntS = w & 1;     // dk-tile / v-col-tile
  const bool outw = (w < 4);               // out tile (mtS, ntS) for mtS in {0,1}

  f32x16 s = z16();

  const int wr = tid >> 3, wc16 = (tid & 7) * 16;
  const int kr = tid >> 2, kc16 = (tid & 3) * 16;
  const int ur = tid >> 3, uc8 = (tid & 7) * 8;

  short8 stW0, stW1, stK0, stK1, stU, stM, qb[8];
  float wcn = 0.f;

  auto issue = [&](int c){
    const unsigned short* rec = recs + (size_t)c * REC;
    stW0 = *(const short8*)(rec + WOFF + wr*128 + wc16);
    stW1 = *(const short8*)(rec + WOFF + wr*128 + wc16 + 8);
    stK0 = *(const short8*)(rec + KOFF + kr*64 + kc16);
    stK1 = *(const short8*)(rec + KOFF + kr*64 + kc16 + 8);
    stU  = *(const short8*)(rec + UOFF + (vh*64 + ur)*64 + uc8);
    stM  = *(const short8*)(rec + MOFF + ur*64 + uc8);
    if (outw) {
      #pragma unroll
      for (int kt = 0; kt < 8; ++kt)
        qb[kt] = *(const short8*)(rec + QOFF + (32*mtS + (lane & 31))*DD + kt*16 + ((lane >> 5) << 3));
    }
    wcn = wcsh[c];
  };
  auto dswrite = [&](int par){
    unsigned short* bw = a + (par ? OW1 : OW0);
    *(short8*)&bw[wr*SK + wc16]     = stW0;
    *(short8*)&bw[wr*SK + wc16 + 8] = stW1;
    unsigned short* bk = a + (par ? OK1 : OK0);
    *(short8*)&bk[kr*SU + kc16]     = stK0;
    *(short8*)&bk[kr*SU + kc16 + 8] = stK1;
    unsigned short* bu = a + (par ? OU1 : OU0);
    *(short8*)&bu[ur*SU + uc8] = stU;
    unsigned short* bm = a + (par ? OM1 : OM0);
    *(short8*)&bm[ur*SU + uc8] = stM;
  };

  issue(0);
  float wc_cur = wcn;
  dswrite(0);
  stq(a+OS0, SK, 32*ntS, 32*mtS, lane, s);   // S0 = 0
  BAR();

  for (int c = 0; c < NCH; ++c) {
    const int cur = c & 1;
    const unsigned short* W_ = a + (cur ? OW1 : OW0);
    const unsigned short* K_ = a + (cur ? OK1 : OK0);
    const unsigned short* U_ = a + (cur ? OU1 : OU0);
    const unsigned short* M_ = a + (cur ? OM1 : OM0);
    const unsigned short* S_ = a + (cur ? OS1 : OS0);
    unsigned short* Sn       = a + (cur ? OS0 : OS1);

    // Oq = Q~ . S0
    f32x16 oq = z16();
    if (outw) {
      #pragma unroll
      for (int kt = 0; kt < 8; ++kt)
        oq = MM32(qb[kt], frg(S_, SK, 32*ntS, kt, lane), oq);
    }
    if (c < NCH-1) issue(c+1);

    // Delta = U + W' . S0 (per-wave redundant for its v-col), -> ΔT scratch
    {
      f32x16 d0 = gemm32<8>(W_, SK, 0,  S_, SK, 32*ntS, z16(), lane);
      f32x16 d1 = gemm32<8>(W_, SK, 32, S_, SK, 32*ntS, z16(), lane);
      const int nn = 32*ntS + (lane & 31), hh = (lane >> 5) << 2;
      #pragma unroll
      for (int q = 0; q < 4; ++q) {
        ushort4v u0 = *(const ushort4v*)&U_[nn*SU + 0  + 8*q + hh];
        ushort4v u1 = *(const ushort4v*)&U_[nn*SU + 32 + 8*q + hh];
        ushort4v p0, p1;
        #pragma unroll
        for (int si = 0; si < 4; ++si) {
          p0[si] = f2bf(d0[4*q+si] + bf2f(u0[si]));
          p1[si] = f2bf(d1[4*q+si] + bf2f(u1[si]));
        }
        *(ushort4v*)&a[ODT + nn*SU + 0  + 8*q + hh] = p0;
        *(ushort4v*)&a[ODT + nn*SU + 32 + 8*q + hh] = p1;
      }
    }

    // S = wc*S + KST . Delta
    {
      f32x16 sa;
      #pragma unroll
      for (int r = 0; r < 16; ++r) sa[r] = s[r] * wc_cur;
      s = gemm32<4>(K_, SU, 32*mtS, a+ODT, SU, 32*ntS, sa, lane);
    }

    // out = Oq + M . Delta -> global
    if (outw) {
      f32x16 o = gemm32<4>(M_, SU, 32*mtS, a+ODT, SU, 32*ntS, oq, lane);
      const int vv = 32*ntS + (lane & 31), hh = (lane >> 5) << 2;
      float* ob = op + (size_t)(c*CC + 32*mtS) * DD + vv;
      #pragma unroll
      for (int q = 0; q < 4; ++q)
        #pragma unroll
        for (int si = 0; si < 4; ++si)
          ob[(size_t)(si + 8*q + hh) * DD] = o[4*q + si];
    }

    stq(Sn, SK, 32*ntS, 32*mtS, lane, s);
    if (c < NCH-1) dswrite(cur ^ 1);
    wc_cur = wcn;
    BAR();
  }

  // final state
  {
    float* fsp = FS + (size_t)head * DD * DD + vh * 64;
    const int nn = 32*ntS + (lane & 31), hh = (lane >> 5) << 2;
    #pragma unroll
    for (int q = 0; q < 4; ++q)
      #pragma unroll
      for (int si = 0; si < 4; ++si)
        fsp[(size_t)(32*mtS + si + 8*q + hh) * DD + nn] = s[4*q + si];
  }
}

// ================================ fallback (R3, verified) ================================
__global__ __launch_bounds__(512, 1)
void gdn_chunk2(const float* __restrict__ Qg, const float* __restrict__ Kg,
                const float* __restrict__ Vg, const float* __restrict__ Gg,
                const float* __restrict__ Bg,
                float* __restrict__ Out, float* __restrict__ FS)
{
  __shared__ __align__(16) unsigned short sKc[64*SK];
  __shared__ __align__(16) unsigned short sQc[64*SK];
  __shared__ __align__(16) unsigned short sS0T[64*SK];
  __shared__ __align__(16) unsigned short sVc[64*S64];
  __shared__ __align__(16) unsigned short sVT[64*S64];
  __shared__ __align__(16) unsigned short sM[64*S64];
  __shared__ __align__(16) unsigned short sAr[8*SLOT];
  __shared__ float sbe2[2][64], swv2[2][64], swiv2[2][64];

  const int tid  = threadIdx.x;
  const int w    = tid >> 6;
  const int lane = tid & 63;
  const int half = w >> 2;
  const int j    = w & 3;
  const int mt   = j >> 1, nt = j & 1;
  const int mtS  = w >> 1, ntS = w & 1;
  const int mtK  = w >> 2, ntK = w & 3;
  const int head = blockIdx.x % NH;
  const int vh   = blockIdx.x / NH;

  const size_t rb = (size_t)head * SEQL * DD;
  const float* qp = Qg + rb;
  const float* kp = Kg + rb;
  const float* vp = Vg + rb + vh * 64;
  const float* gp = Gg + (size_t)head * SEQL;
  const float* bp = Bg + (size_t)head * SEQL;
  float* op  = Out + rb + vh * 64;
  float* fsp = FS + (size_t)head * DD * DD + vh * 64;

  const int lrow = tid >> 3;
  const int c16  = (tid & 7) * 16;
  const int c8   = (tid & 7) * 8;

  unsigned short* const sl0 = sAr + 0*SLOT;
  unsigned short* const sl1 = sAr + 1*SLOT;
  unsigned short* const sl2 = sAr + 2*SLOT;
  unsigned short* const sl3 = sAr + 3*SLOT;
  unsigned short* const sl4 = sAr + 4*SLOT;
  unsigned short* const sl5 = sAr + 5*SLOT;
  unsigned short* const sl6 = sAr + 6*SLOT;
  unsigned short* const sl7 = sAr + 7*SLOT;

  f32x16 s = z16(), oacc = z16();
  f32x4 kr[4], qr[4], vr[2]; float gr = 0.f, br = 0.f;

  auto prefetch = [&](int t0p){
    const float* kb = kp + (size_t)(t0p + lrow) * DD + c16;
    const float* qb = qp + (size_t)(t0p + lrow) * DD + c16;
    const float* vb = vp + (size_t)(t0p + lrow) * DD + c8;
    #pragma unroll
    for (int i = 0; i < 4; ++i) { kr[i] = *(const f32x4*)(kb + 4*i); qr[i] = *(const f32x4*)(qb + 4*i); }
    #pragma unroll
    for (int i = 0; i < 2; ++i) vr[i] = *(const f32x4*)(vb + 4*i);
    if (w == 7) { gr = gp[t0p + lane]; br = bp[t0p + lane]; }
  };
  auto scan_to = [&](int p){
    if (w == 7) {
      float sc = gr;
      #pragma unroll
      for (int d = 1; d < 64; d <<= 1) { float t = __shfl_up(sc, d); if (lane >= d) sc += t; }
      swv2[p][lane]  = __expf(sc);
      swiv2[p][lane] = __expf(-sc);
      sbe2[p][lane]  = br;
    }
  };

  prefetch(0);
  scan_to(0);
  BAR();

  for (int tc = 0; tc < NCH; ++tc) {
    const int t0 = tc * CC;
    const int cur = tc & 1, nxt = cur ^ 1;
    {
      float ssk = 0.f, ssq = 0.f;
      #pragma unroll
      for (int i = 0; i < 4; ++i) {
        ssk += kr[i][0]*kr[i][0] + kr[i][1]*kr[i][1] + kr[i][2]*kr[i][2] + kr[i][3]*kr[i][3];
        ssq += qr[i][0]*qr[i][0] + qr[i][1]*qr[i][1] + qr[i][2]*qr[i][2] + qr[i][3]*qr[i][3];
      }
      ssk += __shfl_xor(ssk, 1); ssk += __shfl_xor(ssk, 2); ssk += __shfl_xor(ssk, 4);
      ssq += __shfl_xor(ssq, 1); ssq += __shfl_xor(ssq, 2); ssq += __shfl_xor(ssq, 4);
      const float ik = 1.f / fmaxf(sqrtf(ssk), 1e-6f);
      const float iq = 0.08838834764831845f / fmaxf(sqrtf(ssq), 1e-6f) * swv2[cur][lrow];
      #pragma unroll
      for (int i = 0; i < 4; ++i) {
        ushort4v pk, pq;
        #pragma unroll
        for (int r = 0; r < 4; ++r) { pk[r] = f2bf(kr[i][r] * ik); pq[r] = f2bf(qr[i][r] * iq); }
        *(ushort4v*)&sKc[lrow*SK + c16 + 4*i] = pk;
        *(ushort4v*)&sQc[lrow*SK + c16 + 4*i] = pq;
      }
      #pragma unroll
      for (int i = 0; i < 2; ++i) {
        ushort4v pv;
        #pragma unroll
        for (int r = 0; r < 4; ++r) pv[r] = f2bf(vr[i][r]);
        *(ushort4v*)&sVc[lrow*S64 + c8 + 4*i] = pv;
      }
    }
    stq(sS0T, SK, 32*ntS, 32*mtS, lane, s);
    prefetch(tc < NCH-1 ? (tc+1)*CC : t0);
    BAR();

    if (half == 0) {
      f32x16 aa = gemm32<8>(sKc, SK, 32*mt, sKc, SK, 32*nt, z16(), lane);
      const int nn = 32*nt + (lane & 31), hh = (lane >> 5) << 2;
      #pragma unroll
      for (int q = 0; q < 4; ++q) {
        ushort4v pR, pL, pPT, pP;
        #pragma unroll
        for (int si = 0; si < 4; ++si) {
          const int r = 4*q + si, mm = 32*mt + 8*q + hh + si;
          const float S = aa[r];
          const float av  = (mm > nn) ? sbe2[cur][mm]*swv2[cur][mm]*swiv2[cur][nn]*S : 0.f;
          const float atr = (nn > mm) ? sbe2[cur][nn]*swv2[cur][nn]*swiv2[cur][mm]*S : 0.f;
          pR[si]  = f2bf(av);
          pL[si]  = f2bf(atr);
          pPT[si] = f2bf(((mm==nn)?1.f:0.f) - av);
          pP[si]  = f2bf(((mm==nn)?1.f:0.f) - atr);
        }
        const int off = nn*S64 + 32*mt + 8*q + hh;
        *(ushort4v*)&sl1[off] = pR;
        *(ushort4v*)&sl0[off] = pL;
        *(ushort4v*)&sl5[off] = pPT;
        *(ushort4v*)&sl4[off] = pP;
      }
    } else {
      f32x16 aa = gemm32<8>(sKc, SK, 32*mt, sQc, SK, 32*nt, z16(), lane);
      const int nn = 32*nt + (lane & 31), hh = (lane >> 5) << 2;
      #pragma unroll
      for (int q = 0; q < 4; ++q) {
        ushort4v pv;
        #pragma unroll
        for (int si = 0; si < 4; ++si) {
          const int r = 4*q + si, mm = 32*mt + 8*q + hh + si;
          pv[si] = f2bf((mm <= nn) ? aa[r]*swiv2[cur][mm] : 0.f);
        }
        *(ushort4v*)&sM[nn*S64 + 32*mt + 8*q + hh] = pv;
      }
    }
    BAR();

    if (half == 0) {
      f32x16 aa = gemm32<4>(sl0, S64, 32*mt, sl1, S64, 32*nt, z16(), lane);
      stq(sl3, S64, 32*nt, 32*mt, lane, aa);
      f32x16 bb = z16();
      #pragma unroll
      for (int kk = 0; kk < 2; ++kk) {
        const int kt = 2*nt + kk;
        bb = MM32(frg(sVc, S64, 32*mt, kt, lane), ifrag(32*nt, kt, lane), bb);
      }
      stq(sVT, S64, 32*nt, 32*mt, lane, bb);
    } else {
      f32x16 aa = gemm32<4>(sl1, S64, 32*mt, sl0, S64, 32*nt, z16(), lane);
      stq(sl2, S64, 32*nt, 32*mt, lane, aa);
      oacc = gemm32<8>(sQc, SK, 32*mt, sS0T, SK, 32*nt, z16(), lane);
    }
    BAR();

    {
      unsigned short* const inL[3]   = { sl2, sl0, sl2 };
      unsigned short* const inR[3]   = { sl3, sl1, sl3 };
      unsigned short* const outL[3]  = { sl0, sl2, sl0 };
      unsigned short* const outR[3]  = { sl1, sl3, sl1 };
      unsigned short* const inP[3]   = { sl4, sl7, sl5 };
      unsigned short* const inPT[3]  = { sl5, sl6, sl4 };
      unsigned short* const outP[3]  = { sl7, sl5, sl7 };
      unsigned short* const outPT[3] = { sl6, sl4, sl6 };
      #pragma unroll
      for (int lev = 0; lev < 3; ++lev) {
        if (half == 0) {
          f32x16 aa = gemm32<4>(inL[lev], S64, 32*mt, inR[lev], S64, 32*nt, z16(), lane);
          stq(outR[lev], S64, 32*nt, 32*mt, lane, aa);
          f32x16 p = ldq(inPT[lev], S64, 32*nt, 32*mt, lane);
          p = gemm32<4>(inP[lev], S64, 32*mt, inR[lev], S64, 32*nt, p, lane);
          stq(outPT[lev], S64, 32*nt, 32*mt, lane, p);
        } else {
          f32x16 aa = gemm32<4>(inR[lev], S64, 32*mt, inL[lev], S64, 32*nt, z16(), lane);
          stq(outL[lev], S64, 32*nt, 32*mt, lane, aa);
          f32x16 p = ldq(inP[lev], S64, 32*nt, 32*mt, lane);
          p = gemm32<4>(inR[lev], S64, 32*mt, inP[lev], S64, 32*nt, p, lane);
          stq(outP[lev], S64, 32*nt, 32*mt, lane, p);
        }
        BAR();
      }
    }

    if (half == 0) {
      f32x16 aa = gemm32<4>(sl0, S64, 32*mt, sl1, S64, 32*nt, z16(), lane);
      stq(sl2, S64, 32*nt, 32*mt, lane, aa);
    } else {
      f32x16 p = ldq(sl7, S64, 32*nt, 32*mt, lane);
      p = gemm32<4>(sl1, S64, 32*mt, sl7, S64, 32*nt, p, lane);
      stq(sl4, S64, 32*nt, 32*mt, lane, p);
    }
    BAR();

    if (half == 0) {
      f32x16 p = ldq(sl4, S64, 32*nt, 32*mt, lane);
      p = gemm32<4>(sl2, S64, 32*mt, sl4, S64, 32*nt, p, lane);
      const int nn = 32*nt + (lane & 31), hh = (lane >> 5) << 2;
      #pragma unroll
      for (int q = 0; q < 4; ++q) {
        ushort4v p2, p3;
        #pragma unroll
        for (int si = 0; si < 4; ++si) {
          const int r = 4*q + si, mm = 32*mt + 8*q + hh + si;
          const float t = p[r];
          p2[si] = f2bf(-t * sbe2[cur][mm] * swv2[cur][mm]);
          p3[si] = f2bf( t * sbe2[cur][mm]);
        }
        const int off = nn*S64 + 32*mt + 8*q + hh;
        *(ushort4v*)&sl1[off] = p2;
        *(ushort4v*)&sl5[off] = p3;
      }
    } else {
      f32x16 zz = gemm32<8>(sKc, SK, 32*mt, sS0T, SK, 32*nt, z16(), lane);
      stq(sl0, S64, 32*nt, 32*mt, lane, zz);
    }
    {
      f32x16 aa = z16();
      #pragma unroll
      for (int kk = 0; kk < 2; ++kk) {
        const int kt = 2*ntK + kk;
        aa = MM32(frg(sKc, SK, 32*mtK, kt, lane), ifrag(32*ntK, kt, lane), aa);
      }
      stq(sl6, S64, 32*ntK, 32*mtK, lane, aa);
    }
    BAR();

    if (half == 0) {
      f32x16 d = gemm32<4>(sl5, S64, 32*mt, sVT, S64, 32*nt, z16(), lane);
      d = gemm32<4>(sl1, S64, 32*mt, sl0, S64, 32*nt, d, lane);
      const int nn = 32*nt + (lane & 31), hh = (lane >> 5) << 2;
      const float w63 = swv2[cur][63];
      #pragma unroll
      for (int q = 0; q < 4; ++q) {
        ushort4v pt, ps;
        #pragma unroll
        for (int si = 0; si < 4; ++si) {
          const int r = 4*q + si, mm = 32*mt + 8*q + hh + si;
          pt[si] = f2bf(d[r]);
          ps[si] = f2bf(d[r] * w63 * swiv2[cur][mm]);
        }
        const int off = nn*S64 + 32*mt + 8*q + hh;
        *(ushort4v*)&sl3[off] = pt;
        *(ushort4v*)&sl2[off] = ps;
      }
    }
    scan_to(nxt);
    {
      const float w63 = swv2[cur][63];
      #pragma unroll
      for (int r = 0; r < 16; ++r) s[r] *= w63;
    }
    BAR();

    s = gemm32<4>(sl6, S64, 32*mtS, sl2, S64, 32*ntS, s, lane);
    if (half == 1) {
      f32x16 o = oacc;
      o = gemm32<4>(sM, S64, 32*mt, sl3, S64, 32*nt, o, lane);
      const int nn = 32*nt + (lane & 31), hh = (lane >> 5) << 2;
      #pragma unroll
      for (int q = 0; q < 4; ++q)
        #pragma unroll
        for (int si = 0; si < 4; ++si)
          op[(size_t)(t0 + 32*mt + 8*q + hh + si) * DD + nn] = o[4*q + si];
    }
    BAR();
  }

  {
    const int nn = 32*ntS + (lane & 31), hh = (lane >> 5) << 2;
    #pragma unroll
    for (int q = 0; q < 4; ++q)
      #pragma unroll
      for (int si = 0; si < 4; ++si)
        fsp[(size_t)(32*mtS + 8*q + hh + si) * DD + nn] = s[4*q + si];
  }
}

extern "C" void kernel_launch(void* const* d_in, const int* in_sizes, int n_in,
                              void* d_out, int out_size, void* d_ws, size_t ws_size,
                              hipStream_t stream) {
  const float* Q = (const float*)d_in[0];
  const float* K = (const float*)d_in[1];
  const float* V = (const float*)d_in[2];
  const float* G = (const float*)d_in[3];
  const float* B = (const float*)d_in[4];
  float* Out = (float*)d_out;
  float* FS  = Out + (size_t)NH * SEQL * DD;

  const size_t WS_NEED = (size_t)NH * NCH * REC * 2 + (size_t)NH * NCH * 4;
  if (ws_size >= WS_NEED) {
    unsigned short* wsp = (unsigned short*)d_ws;
    float* wcs = (float*)(wsp + (size_t)NH * NCH * REC);
    hipLaunchKernelGGL(gdn_prep, dim3(NH*NCH), dim3(512), 0, stream, Q, K, V, G, B, wsp, wcs);
    hipLaunchKernelGGL(gdn_scan, dim3(NH*2), dim3(512), 0, stream, wsp, wcs, Out, FS);
  } else {
    hipLaunchKernelGGL(gdn_chunk2, dim3(NH*2), dim3(512), 0, stream, Q, K, V, G, B, Out, FS);
  }
}